// Round 13
// baseline (413.241 us; speedup 1.0000x reference)
//
#include <hip/hip_runtime.h>

// ---------------------------------------------------------------------------
// GIN 2-layer forward (bf16 features, MFMA GEMMs, CSR gather segment-sum):
//   CSR bucket edges by dst (hist -> parallel scan -> fill)
//   p1 = bf16( x @ w1a )                      [b1a cancels in BN]
//   s1 = bf16( p1[n] + gather-sum )           (fused column stats)
//   h1 = bf16( relu( relu(BN(s1)) @ w1b + b1b ) )   [BN affine in-kernel]
//   p2 = bf16( h1 @ w2a )                     [b2a cancels in BN]
//   s2 = bf16( p2[n] + gather-sum )
//   out = log_softmax( relu(BN(s2)) @ w2b + b2b )  fp32, fused epilogue
// R12: segsum_du = DUAL-NODE lane-split gather. Wave halves serve two nodes;
// one gather instruction covers 2 edges (2 rows). Same 8-deep pipeline as the
// proven R5 loop; per-edge VMEM-instruction count halved (the measured bound:
// segsum<64> == segsum<128> time == instruction count, not bytes).
// ---------------------------------------------------------------------------

typedef unsigned short u16;
typedef unsigned int u32;
typedef __attribute__((ext_vector_type(8))) short short8;
typedef __attribute__((ext_vector_type(4))) short short4v;
typedef __attribute__((ext_vector_type(4))) float f32x4;

#define DEV_INLINE __device__ __forceinline__

DEV_INLINE void atomAddF(float* p, float v) { unsafeAtomicAdd(p, v); }

DEV_INLINE u16 f2bf(float f) {
    unsigned u = __float_as_uint(f);
    u += 0x7fffu + ((u >> 16) & 1u);   // round-to-nearest-even
    return (u16)(u >> 16);
}
DEV_INLINE float bf2f(u16 h) { return __uint_as_float(((unsigned)h) << 16); }

// ---------------------------------------------------------------------------
// Weight prep (all 4 weights, one launch): W[K][NOUT] fp32 -> frag-ordered
// bf16 (MFMA A-operand, swapped). unit=(ct,kc,lane): 8 bf16 for
// col=ct*16+(lane&15), k=kc*32+(lane>>4)*8+j.
// ---------------------------------------------------------------------------
__global__ __launch_bounds__(256) void wprep4_k(
    const float* __restrict__ w1a, const float* __restrict__ w1b,
    const float* __restrict__ w2a, const float* __restrict__ w2b,
    short* __restrict__ o1a, short* __restrict__ o1b,
    short* __restrict__ o2a, short* __restrict__ o2b)
{
    int b = blockIdx.x;
    const float* W; short* wf; int K, NOUT;
    if (b < 8)       { W = w1a; wf = o1a; K = 128; NOUT = 128; }
    else if (b < 16) { W = w1b; wf = o1b; K = 128; NOUT = 128; b -= 8; }
    else if (b < 20) { W = w2a; wf = o2a; K = 128; NOUT = 64;  b -= 16; }
    else             { W = w2b; wf = o2b; K = 64;  NOUT = 64;  b -= 20; }
    const int u = b * 256 + threadIdx.x;
    const int units = (NOUT / 16) * (K / 32) * 64;
    if (u >= units) return;
    const int per_ct = (K / 32) * 64;
    const int ct = u / per_ct;
    const int rem = u % per_ct;
    const int kc = rem >> 6;
    const int l = rem & 63;
    const int col = ct * 16 + (l & 15);
    const int k0 = kc * 32 + (l >> 4) * 8;
    short8 pk;
#pragma unroll
    for (int j = 0; j < 8; j++)
        pk[j] = (short)f2bf(W[(size_t)(k0 + j) * NOUT + col]);
    *(short8*)&wf[(size_t)u * 8] = pk;
}

// ---------------------------------------------------------------------------
// MFMA GEMM, BM=64 rows/block: out[M][NC] = f(A[M][KD]) @ W
// f = identity or BN+ReLU with sc/sh computed IN-KERNEL from sum/sumsq.
// 256 threads = 4 waves; wave w owns row-tile w; CT col-tiles each.
// ---------------------------------------------------------------------------
template <int KD, int NC, bool ABF16, bool BNIN, bool BIAS, bool RELUOUT,
          bool LOGSM, bool OBF16>
__global__ __launch_bounds__(256) void mgemm(
    const void* __restrict__ Ap, const short* __restrict__ Wf,
    const float* __restrict__ sum, const float* __restrict__ sumsq,
    const float* __restrict__ g, const float* __restrict__ be, float invN,
    const float* __restrict__ bias, void* __restrict__ outp, int M)
{
    constexpr int BM = 64;
    constexpr int KC = KD / 32;     // 32-wide k chunks
    constexpr int CT = NC / 16;     // 16-wide col tiles
    constexpr int KQ = KD / 4;      // elements per staging thread
    __shared__ short Asl[BM * KD];
    __shared__ short Bsl[NC * KD];
    __shared__ float scb[BNIN ? KD : 1];
    __shared__ float shb[BNIN ? KD : 1];

    const int t = threadIdx.x;
    const int l = t & 63;
    const int w = t >> 6;

    // ---- fused BN-affine from stats (replaces bnfinal kernel) ----
    if constexpr (BNIN) {
        if (t < KD) {
            const float m = sum[t] * invN;
            const float v = sumsq[t] * invN - m * m;
            const float r = rsqrtf(v + 1e-5f);
            const float s = g[t] * r;
            scb[t] = s;
            shb[t] = be[t] - m * s;
        }
        __syncthreads();
    }

    // ---- stage B: frag-ordered weights, linear copy ----
    {
        const float4* src = (const float4*)Wf;
        float4* dst = (float4*)Bsl;
        constexpr int NU = NC * KD / 8;
#pragma unroll
        for (int u = t; u < NU; u += 256) dst[u] = src[u];
    }
    // ---- stage A: 4 threads per row, KQ elems each -> (BN+ReLU) -> frags ----
    {
        const int r = t >> 2;
        const int q = t & 3;
        const int grow = blockIdx.x * BM + r;
        const int rt = r >> 4;
        u16 hv[KQ];
        if (grow < M) {
            if constexpr (ABF16) {
                const u16* ap = (const u16*)Ap + (size_t)grow * KD + q * KQ;
#pragma unroll
                for (int i = 0; i < KQ / 8; i++)
                    *(short8*)&hv[i * 8] = ((const short8*)ap)[i];
                if constexpr (BNIN) {
#pragma unroll
                    for (int i = 0; i < KQ; i++) {
                        const int k = q * KQ + i;
                        hv[i] = f2bf(fmaxf(0.f, bf2f(hv[i]) * scb[k] + shb[k]));
                    }
                }
            } else {
                const float* ap = (const float*)Ap + (size_t)grow * KD + q * KQ;
#pragma unroll
                for (int i = 0; i < KQ / 4; i++) {
                    const float4 v = ((const float4*)ap)[i];
                    float f0 = v.x, f1 = v.y, f2 = v.z, f3 = v.w;
                    if constexpr (BNIN) {
                        const int k = q * KQ + i * 4;
                        f0 = fmaxf(0.f, f0 * scb[k + 0] + shb[k + 0]);
                        f1 = fmaxf(0.f, f1 * scb[k + 1] + shb[k + 1]);
                        f2 = fmaxf(0.f, f2 * scb[k + 2] + shb[k + 2]);
                        f3 = fmaxf(0.f, f3 * scb[k + 3] + shb[k + 3]);
                    }
                    hv[i * 4 + 0] = f2bf(f0); hv[i * 4 + 1] = f2bf(f1);
                    hv[i * 4 + 2] = f2bf(f2); hv[i * 4 + 3] = f2bf(f3);
                }
            }
        } else {
#pragma unroll
            for (int i = 0; i < KQ; i++) hv[i] = 0;
        }
#pragma unroll
        for (int gg = 0; gg < KQ / 8; gg++) {
            const int k0 = q * KQ + gg * 8;
            const int kc = k0 >> 5;
            const int lane = (r & 15) + ((k0 >> 3) & 3) * 16;
            *(short8*)&Asl[((rt * KC + kc) * 64 + lane) * 8] =
                *(short8*)&hv[gg * 8];
        }
    }
    __syncthreads();

    // ---- MFMA: wave w owns row-tile w x all col-tiles ----
    f32x4 acc[CT];
#pragma unroll
    for (int c = 0; c < CT; c++) acc[c] = (f32x4){0.f, 0.f, 0.f, 0.f};

#pragma unroll
    for (int kc = 0; kc < KC; kc++) {
        const short8 x0 = *(const short8*)&Asl[((w * KC + kc) * 64 + l) * 8];
#pragma unroll
        for (int ct = 0; ct < CT; ct++) {
            const short8 wb = *(const short8*)&Bsl[((ct * KC + kc) * 64 + l) * 8];
            acc[ct] = __builtin_amdgcn_mfma_f32_16x16x32_bf16(wb, x0, acc[ct], 0, 0, 0);
        }
    }

    // ---- epilogue: lane l holds row (l&15), cols (l>>4)*4+{0..3} of tile ----
    const int cbase = (l >> 4) * 4;
    const int grow = blockIdx.x * BM + w * 16 + (l & 15);
    if constexpr (!LOGSM) {
        if (grow < M) {
#pragma unroll
            for (int ct = 0; ct < CT; ct++) {
                f32x4 o = acc[ct];
                if constexpr (BIAS) {
                    const float4 bv = *(const float4*)&bias[ct * 16 + cbase];
                    o[0] += bv.x; o[1] += bv.y; o[2] += bv.z; o[3] += bv.w;
                }
                if constexpr (RELUOUT) {
#pragma unroll
                    for (int j = 0; j < 4; j++) o[j] = fmaxf(o[j], 0.f);
                }
                if constexpr (OBF16) {
                    short4v o16;
#pragma unroll
                    for (int j = 0; j < 4; j++) o16[j] = (short)f2bf(o[j]);
                    *(short4v*)&((u16*)outp)[(size_t)grow * NC + ct * 16 + cbase] = o16;
                } else {
                    *(f32x4*)&((float*)outp)[(size_t)grow * NC + ct * 16 + cbase] = o;
                }
            }
        }
    } else {
        // fused row log_softmax (row spread across lanes l, l^16, l^32, l^48)
        float v[CT * 4];
#pragma unroll
        for (int ct = 0; ct < CT; ct++) {
            const float4 bv = *(const float4*)&bias[ct * 16 + cbase];
            v[ct * 4 + 0] = acc[ct][0] + bv.x;
            v[ct * 4 + 1] = acc[ct][1] + bv.y;
            v[ct * 4 + 2] = acc[ct][2] + bv.z;
            v[ct * 4 + 3] = acc[ct][3] + bv.w;
        }
        float m = v[0];
#pragma unroll
        for (int j = 1; j < CT * 4; j++) m = fmaxf(m, v[j]);
        m = fmaxf(m, __shfl_xor(m, 16));
        m = fmaxf(m, __shfl_xor(m, 32));
        float s = 0.f;
#pragma unroll
        for (int j = 0; j < CT * 4; j++) s += __expf(v[j] - m);
        s += __shfl_xor(s, 16);
        s += __shfl_xor(s, 32);
        const float lg = m + __logf(s);
        if (grow < M) {
#pragma unroll
            for (int ct = 0; ct < CT; ct++) {
                f32x4 o;
#pragma unroll
                for (int j = 0; j < 4; j++) o[j] = v[ct * 4 + j] - lg;
                *(f32x4*)&((float*)outp)[(size_t)grow * NC + ct * 16 + cbase] = o;
            }
        }
    }
}

// ---------------------------------------------------------------------------
// CSR build: histogram, 3-kernel parallel exclusive scan, bucket fill.
// ---------------------------------------------------------------------------
__global__ __launch_bounds__(256) void hist_k(const int* __restrict__ ei,
                                              int* __restrict__ cnt, int E)
{
    const int gid = blockIdx.x * blockDim.x + threadIdx.x;
    const int stride = gridDim.x * blockDim.x;
    for (int e = gid; e < E; e += stride) atomicAdd(&cnt[ei[E + e]], 1);
}

__global__ __launch_bounds__(256) void bsum_k(const int* __restrict__ cnt,
                                              int* __restrict__ bsum, int N)
{
    __shared__ int ws[4];
    const int i = blockIdx.x * 256 + threadIdx.x;
    int v = (i < N) ? cnt[i] : 0;
    for (int d = 32; d; d >>= 1) v += __shfl_xor(v, d, 64);
    if ((threadIdx.x & 63) == 0) ws[threadIdx.x >> 6] = v;
    __syncthreads();
    if (threadIdx.x == 0) bsum[blockIdx.x] = ws[0] + ws[1] + ws[2] + ws[3];
}

// single block; G1 <= 256
__global__ __launch_bounds__(256) void bscan_k(const int* __restrict__ bsum,
                                               int* __restrict__ bpre, int G1)
{
    __shared__ int part[256];
    const int t = threadIdx.x;
    const int v = (t < G1) ? bsum[t] : 0;
    part[t] = v;
    __syncthreads();
    for (int d = 1; d < 256; d <<= 1) {
        const int u = (t >= d) ? part[t - d] : 0;
        __syncthreads();
        part[t] += u;
        __syncthreads();
    }
    bpre[t] = part[t] - v;   // exclusive
}

__global__ __launch_bounds__(256) void offs_k(const int* __restrict__ cnt,
                                              const int* __restrict__ bpre,
                                              int* __restrict__ off,
                                              int* __restrict__ cursor,
                                              int N, int E)
{
    __shared__ int part[256];
    const int t = threadIdx.x;
    const int i = blockIdx.x * 256 + t;
    const int v = (i < N) ? cnt[i] : 0;
    part[t] = v;
    __syncthreads();
    for (int d = 1; d < 256; d <<= 1) {
        const int u = (t >= d) ? part[t - d] : 0;
        __syncthreads();
        part[t] += u;
        __syncthreads();
    }
    if (i < N) {
        const int o = bpre[blockIdx.x] + part[t] - v;
        off[i] = o;
        cursor[i] = o;
    }
    if (blockIdx.x == 0 && t == 0) off[N] = E;
}

__global__ __launch_bounds__(256) void fill_k(const int* __restrict__ ei,
                                              int* __restrict__ cursor,
                                              int* __restrict__ srcs, int E)
{
    const int gid = blockIdx.x * blockDim.x + threadIdx.x;
    const int stride = gridDim.x * blockDim.x;
    for (int e = gid; e < E; e += stride) {
        const int s = ei[e];
        const int d = ei[E + e];
        const int pos = atomicAdd(&cursor[d], 1);
        srcs[pos] = s;
    }
}

// ---------------------------------------------------------------------------
// DUAL-NODE gather segment-sum (bf16 in/out) + fused column stats.
// Lanes 0-31 serve node A, lanes 32-63 node B (a consecutive pair): one
// gather instruction covers 2 edges. R5's 8-deep pipeline preserved.
// C=64: 32 lanes x dword = 128B row; C=128: 32 lanes x dwordx2 = 256B row.
// Per-node edge order identical to R5 -> same numerics.
// ---------------------------------------------------------------------------
template <int C>
__global__ __launch_bounds__(256) void segsum_du(
    const u16* __restrict__ p, const int* __restrict__ off,
    const int* __restrict__ srcs, u16* __restrict__ out,
    float* __restrict__ sum, float* __restrict__ sumsq, int N)
{
    constexpr int VPL = C / 32;          // channels per lane (2 or 4)
    __shared__ float redS[4][64][VPL];
    __shared__ float redQ[4][64][VPL];

    const int wv = threadIdx.x >> 6;
    const int l  = threadIdx.x & 63;
    const int hl = l & 31;               // lane within half
    const int base = blockIdx.x * 32;

    float ss[VPL], qq[VPL];
#pragma unroll
    for (int v = 0; v < VPL; v++) { ss[v] = 0.f; qq[v] = 0.f; }

    for (int i = 0; i < 4; i++) {
        const int n0 = base + wv * 2 + i * 8;    // pair base (wave-uniform)
        if (n0 >= N) break;
        const int n = n0 + (l >> 5);             // this half's node
        const int nc = min(n, N - 1);
        const int lo = off[nc];                  // uniform within half
        const int hi = off[nc + 1];
        const int deg = hi - lo;
        const int dmax = max(deg, __shfl_xor(deg, 32));   // wave-uniform
        const int last = (deg > 0) ? hi - 1 : lo;

        float acc[VPL];
        if constexpr (C == 64) {
            const u32 u = *(const u32*)&p[(size_t)nc * 64 + hl * 2];
            acc[0] = bf2f((u16)u);
            acc[1] = bf2f((u16)(u >> 16));
        } else {
            const uint2 u = *(const uint2*)&p[(size_t)nc * 128 + hl * 4];
            acc[0] = bf2f((u16)u.x);
            acc[1] = bf2f((u16)(u.x >> 16));
            acc[2] = bf2f((u16)u.y);
            acc[3] = bf2f((u16)(u.y >> 16));
        }

        if (dmax > 0) {
            int idx[8];
#pragma unroll
            for (int j = 0; j < 8; j++) idx[j] = srcs[min(lo + j, last)];
            for (int e = 0; e < dmax; e += 8) {
                int nx[8];
#pragma unroll
                for (int j = 0; j < 8; j++)
                    nx[j] = srcs[min(lo + e + 8 + j, last)];   // prefetch
#pragma unroll
                for (int j = 0; j < 8; j++) {
                    const bool live = (e + j) < deg;   // uniform per half
                    if constexpr (C == 64) {
                        const u32 u = *(const u32*)&p[(size_t)idx[j] * 64 + hl * 2];
                        acc[0] += live ? bf2f((u16)u) : 0.f;
                        acc[1] += live ? bf2f((u16)(u >> 16)) : 0.f;
                    } else {
                        const uint2 u = *(const uint2*)&p[(size_t)idx[j] * 128 + hl * 4];
                        acc[0] += live ? bf2f((u16)u.x) : 0.f;
                        acc[1] += live ? bf2f((u16)(u.x >> 16)) : 0.f;
                        acc[2] += live ? bf2f((u16)u.y) : 0.f;
                        acc[3] += live ? bf2f((u16)(u.y >> 16)) : 0.f;
                    }
                }
#pragma unroll
                for (int j = 0; j < 8; j++) idx[j] = nx[j];
            }
        }

        if (n < N) {
            u16 r[VPL];
#pragma unroll
            for (int v = 0; v < VPL; v++) r[v] = f2bf(acc[v]);
            if constexpr (C == 64) {
                *(u32*)&out[(size_t)n * 64 + hl * 2] =
                    (u32)r[0] | ((u32)r[1] << 16);
            } else {
                uint2 o;
                o.x = (u32)r[0] | ((u32)r[1] << 16);
                o.y = (u32)r[2] | ((u32)r[3] << 16);
                *(uint2*)&out[(size_t)n * 128 + hl * 4] = o;
            }
#pragma unroll
            for (int v = 0; v < VPL; v++) {
                const float f = bf2f(r[v]);
                ss[v] += f;
                qq[v] += f * f;
            }
        }
    }

    // block reduce: halves share channels (ch = hl*VPL + v); 4 waves -> wave 0
#pragma unroll
    for (int v = 0; v < VPL; v++) {
        redS[wv][l][v] = ss[v];
        redQ[wv][l][v] = qq[v];
    }
    __syncthreads();
    if (wv == 0 && l < 32) {
#pragma unroll
        for (int v = 0; v < VPL; v++) {
            float a = 0.f, b = 0.f;
#pragma unroll
            for (int w2 = 0; w2 < 4; w2++) {
                a += redS[w2][l][v] + redS[w2][l + 32][v];
                b += redQ[w2][l][v] + redQ[w2][l + 32][v];
            }
            atomAddF(&sum[l * VPL + v], a);
            atomAddF(&sumsq[l * VPL + v], b);
        }
    }
}

extern "C" void kernel_launch(void* const* d_in, const int* in_sizes, int n_in,
                              void* d_out, int out_size, void* d_ws, size_t ws_size,
                              hipStream_t stream)
{
    const float* x   = (const float*)d_in[0];
    const int*   ei  = (const int*)d_in[1];
    const float* w1a = (const float*)d_in[2];
    // d_in[3] = b1a: cancelled by BN
    const float* g1  = (const float*)d_in[4];
    const float* be1 = (const float*)d_in[5];
    const float* w1b = (const float*)d_in[6];
    const float* b1b = (const float*)d_in[7];
    const float* w2a = (const float*)d_in[8];
    // d_in[9] = b2a: cancelled by BN
    const float* g2  = (const float*)d_in[10];
    const float* be2 = (const float*)d_in[11];
    const float* w2b = (const float*)d_in[12];
    const float* b2b = (const float*)d_in[13];
    float* out = (float*)d_out;

    const int N = in_sizes[0] / 128;   // 50000
    const int E = in_sizes[1] / 2;     // 800000

    // ---- workspace layout ----
    u16* buf1 = (u16*)d_ws;                      // N*128 bf16 : p1, then h1
    u16* buf2 = buf1 + (size_t)N * 128;          // N*128 bf16 : s1, then p2|s2
    float* stats = (float*)(buf2 + (size_t)N * 128);  // 1024 floats
    float* sum1 = stats,       *sq1 = stats + 128;
    float* sum2 = stats + 256, *sq2 = stats + 320;
    int* cnt    = (int*)(stats + 1024);          // N
    int* off    = cnt + N;                       // N+1
    int* cursor = off + N + 1;                   // N
    int* srcs   = cursor + N;                    // E
    int* bsum   = srcs + E;                      // 256
    int* bpre   = bsum + 256;                    // 256
    short* w1af = (short*)(bpre + 256);          // 128*128
    short* w1bf = w1af + 128 * 128;              // 128*128
    short* w2af = w1bf + 128 * 128;              // 128*64
    short* w2bf = w2af + 128 * 64;               // 64*64
    u16* p1 = buf1;
    u16* s1 = buf2;
    u16* h1 = buf1;                    // reuse: p1 dead after segsum1
    u16* p2 = buf2;                    // reuse: s1 dead after mgemm2 (N*64)
    u16* s2 = buf2 + (size_t)N * 64;   // upper half

    hipMemsetAsync(stats, 0, 1024 * sizeof(float) + (size_t)N * sizeof(int), stream);

    const int G1 = (N + 255) / 256;
    const int gb = (N + 63) / 64;      // BM=64 -> 782 blocks
    const int gs = (N + 31) / 32;      // segsum: 4 waves x 4 pairs per block
    const float invN = 1.f / N;

    // ---- CSR build ----
    hist_k<<<1024, 256, 0, stream>>>(ei, cnt, E);
    bsum_k<<<G1, 256, 0, stream>>>(cnt, bsum, N);
    bscan_k<<<1, 256, 0, stream>>>(bsum, bpre, G1);
    offs_k<<<G1, 256, 0, stream>>>(cnt, bpre, off, cursor, N, E);
    fill_k<<<1024, 256, 0, stream>>>(ei, cursor, srcs, E);

    // ---- weight prep (one launch for all four) ----
    wprep4_k<<<22, 256, 0, stream>>>(w1a, w1b, w2a, w2b, w1af, w1bf, w2af, w2bf);

    // ---- Layer 1 ----
    mgemm<128, 128, false, false, false, false, false, true>
        <<<gb, 256, 0, stream>>>(x, w1af, nullptr, nullptr, nullptr, nullptr,
                                 0.f, nullptr, p1, N);
    segsum_du<128><<<gs, 256, 0, stream>>>(p1, off, srcs, s1, sum1, sq1, N);
    mgemm<128, 128, true, true, true, true, false, true>
        <<<gb, 256, 0, stream>>>(s1, w1bf, sum1, sq1, g1, be1, invN, b1b, h1, N);

    // ---- Layer 2 (aggregate after projecting to 64ch) ----
    mgemm<128, 64, true, false, false, false, false, true>
        <<<gb, 256, 0, stream>>>(h1, w2af, nullptr, nullptr, nullptr, nullptr,
                                 0.f, nullptr, p2, N);
    segsum_du<64><<<gs, 256, 0, stream>>>(p2, off, srcs, s2, sum2, sq2, N);
    mgemm<64, 64, true, true, true, false, true, false>
        <<<gb, 256, 0, stream>>>(s2, w2bf, sum2, sq2, g2, be2, invN, b2b, out, N);
}

// Round 14
// 395.028 us; speedup vs baseline: 1.0461x; 1.0461x over previous
//
#include <hip/hip_runtime.h>

// ---------------------------------------------------------------------------
// GIN 2-layer forward (bf16 features, MFMA GEMMs, CSR gather segment-sum):
//   CSR bucket edges by dst (hist -> parallel scan -> fill)
//   p1 = bf16( x @ w1a )                      [b1a cancels in BN]
//   s1 = bf16( p1[n] + gather-sum )           (fused column stats)
//   p2 = bf16( relu(BN(s1)) @ w1b + b1b, relu ) @ w2a   [FUSED mgemm23:
//        h1 lives only in registers/LDS; b2a cancels in BN]
//   s2 = bf16( p2[n] + gather-sum )
//   out = log_softmax( relu(BN(s2)) @ w2b + b2b )  fp32, fused epilogue
// segsum = R5's measured-best structure (the 8-variant search R5-R12 proved
// it sits at the per-CU scattered-row-transaction wall); BLKN 4 for occupancy.
// ---------------------------------------------------------------------------

typedef unsigned short u16;
typedef unsigned int u32;
typedef __attribute__((ext_vector_type(8))) short short8;
typedef __attribute__((ext_vector_type(4))) short short4v;
typedef __attribute__((ext_vector_type(4))) float f32x4;

#define DEV_INLINE __device__ __forceinline__

DEV_INLINE void atomAddF(float* p, float v) { unsafeAtomicAdd(p, v); }

DEV_INLINE u16 f2bf(float f) {
    unsigned u = __float_as_uint(f);
    u += 0x7fffu + ((u >> 16) & 1u);   // round-to-nearest-even
    return (u16)(u >> 16);
}
DEV_INLINE float bf2f(u16 h) { return __uint_as_float(((unsigned)h) << 16); }

// ---------------------------------------------------------------------------
// Weight prep (all 4 weights, one launch): W[K][NOUT] fp32 -> frag-ordered
// bf16 (MFMA A-operand, swapped). unit=(ct,kc,lane): 8 bf16 for
// col=ct*16+(lane&15), k=kc*32+(lane>>4)*8+j.
// ---------------------------------------------------------------------------
__global__ __launch_bounds__(256) void wprep4_k(
    const float* __restrict__ w1a, const float* __restrict__ w1b,
    const float* __restrict__ w2a, const float* __restrict__ w2b,
    short* __restrict__ o1a, short* __restrict__ o1b,
    short* __restrict__ o2a, short* __restrict__ o2b)
{
    int b = blockIdx.x;
    const float* W; short* wf; int K, NOUT;
    if (b < 8)       { W = w1a; wf = o1a; K = 128; NOUT = 128; }
    else if (b < 16) { W = w1b; wf = o1b; K = 128; NOUT = 128; b -= 8; }
    else if (b < 20) { W = w2a; wf = o2a; K = 128; NOUT = 64;  b -= 16; }
    else             { W = w2b; wf = o2b; K = 64;  NOUT = 64;  b -= 20; }
    const int u = b * 256 + threadIdx.x;
    const int units = (NOUT / 16) * (K / 32) * 64;
    if (u >= units) return;
    const int per_ct = (K / 32) * 64;
    const int ct = u / per_ct;
    const int rem = u % per_ct;
    const int kc = rem >> 6;
    const int l = rem & 63;
    const int col = ct * 16 + (l & 15);
    const int k0 = kc * 32 + (l >> 4) * 8;
    short8 pk;
#pragma unroll
    for (int j = 0; j < 8; j++)
        pk[j] = (short)f2bf(W[(size_t)(k0 + j) * NOUT + col]);
    *(short8*)&wf[(size_t)u * 8] = pk;
}

// ---------------------------------------------------------------------------
// MFMA GEMM, BM=64 rows/block: out[M][NC] = f(A[M][KD]) @ W
// f = identity or BN+ReLU with sc/sh computed IN-KERNEL from sum/sumsq.
// ---------------------------------------------------------------------------
template <int KD, int NC, bool ABF16, bool BNIN, bool BIAS, bool RELUOUT,
          bool LOGSM, bool OBF16>
__global__ __launch_bounds__(256) void mgemm(
    const void* __restrict__ Ap, const short* __restrict__ Wf,
    const float* __restrict__ sum, const float* __restrict__ sumsq,
    const float* __restrict__ g, const float* __restrict__ be, float invN,
    const float* __restrict__ bias, void* __restrict__ outp, int M)
{
    constexpr int BM = 64;
    constexpr int KC = KD / 32;
    constexpr int CT = NC / 16;
    constexpr int KQ = KD / 4;
    __shared__ short Asl[BM * KD];
    __shared__ short Bsl[NC * KD];
    __shared__ float scb[BNIN ? KD : 1];
    __shared__ float shb[BNIN ? KD : 1];

    const int t = threadIdx.x;
    const int l = t & 63;
    const int w = t >> 6;

    if constexpr (BNIN) {
        if (t < KD) {
            const float m = sum[t] * invN;
            const float v = sumsq[t] * invN - m * m;
            const float r = rsqrtf(v + 1e-5f);
            const float s = g[t] * r;
            scb[t] = s;
            shb[t] = be[t] - m * s;
        }
        __syncthreads();
    }

    {
        const float4* src = (const float4*)Wf;
        float4* dst = (float4*)Bsl;
        constexpr int NU = NC * KD / 8;
#pragma unroll
        for (int u = t; u < NU; u += 256) dst[u] = src[u];
    }
    {
        const int r = t >> 2;
        const int q = t & 3;
        const int grow = blockIdx.x * BM + r;
        const int rt = r >> 4;
        u16 hv[KQ];
        if (grow < M) {
            if constexpr (ABF16) {
                const u16* ap = (const u16*)Ap + (size_t)grow * KD + q * KQ;
#pragma unroll
                for (int i = 0; i < KQ / 8; i++)
                    *(short8*)&hv[i * 8] = ((const short8*)ap)[i];
                if constexpr (BNIN) {
#pragma unroll
                    for (int i = 0; i < KQ; i++) {
                        const int k = q * KQ + i;
                        hv[i] = f2bf(fmaxf(0.f, bf2f(hv[i]) * scb[k] + shb[k]));
                    }
                }
            } else {
                const float* ap = (const float*)Ap + (size_t)grow * KD + q * KQ;
#pragma unroll
                for (int i = 0; i < KQ / 4; i++) {
                    const float4 v = ((const float4*)ap)[i];
                    float f0 = v.x, f1 = v.y, f2 = v.z, f3 = v.w;
                    if constexpr (BNIN) {
                        const int k = q * KQ + i * 4;
                        f0 = fmaxf(0.f, f0 * scb[k + 0] + shb[k + 0]);
                        f1 = fmaxf(0.f, f1 * scb[k + 1] + shb[k + 1]);
                        f2 = fmaxf(0.f, f2 * scb[k + 2] + shb[k + 2]);
                        f3 = fmaxf(0.f, f3 * scb[k + 3] + shb[k + 3]);
                    }
                    hv[i * 4 + 0] = f2bf(f0); hv[i * 4 + 1] = f2bf(f1);
                    hv[i * 4 + 2] = f2bf(f2); hv[i * 4 + 3] = f2bf(f3);
                }
            }
        } else {
#pragma unroll
            for (int i = 0; i < KQ; i++) hv[i] = 0;
        }
#pragma unroll
        for (int gg = 0; gg < KQ / 8; gg++) {
            const int k0 = q * KQ + gg * 8;
            const int kc = k0 >> 5;
            const int lane = (r & 15) + ((k0 >> 3) & 3) * 16;
            *(short8*)&Asl[((rt * KC + kc) * 64 + lane) * 8] =
                *(short8*)&hv[gg * 8];
        }
    }
    __syncthreads();

    f32x4 acc[CT];
#pragma unroll
    for (int c = 0; c < CT; c++) acc[c] = (f32x4){0.f, 0.f, 0.f, 0.f};

#pragma unroll
    for (int kc = 0; kc < KC; kc++) {
        const short8 x0 = *(const short8*)&Asl[((w * KC + kc) * 64 + l) * 8];
#pragma unroll
        for (int ct = 0; ct < CT; ct++) {
            const short8 wb = *(const short8*)&Bsl[((ct * KC + kc) * 64 + l) * 8];
            acc[ct] = __builtin_amdgcn_mfma_f32_16x16x32_bf16(wb, x0, acc[ct], 0, 0, 0);
        }
    }

    const int cbase = (l >> 4) * 4;
    const int grow = blockIdx.x * BM + w * 16 + (l & 15);
    if constexpr (!LOGSM) {
        if (grow < M) {
#pragma unroll
            for (int ct = 0; ct < CT; ct++) {
                f32x4 o = acc[ct];
                if constexpr (BIAS) {
                    const float4 bv = *(const float4*)&bias[ct * 16 + cbase];
                    o[0] += bv.x; o[1] += bv.y; o[2] += bv.z; o[3] += bv.w;
                }
                if constexpr (RELUOUT) {
#pragma unroll
                    for (int j = 0; j < 4; j++) o[j] = fmaxf(o[j], 0.f);
                }
                if constexpr (OBF16) {
                    short4v o16;
#pragma unroll
                    for (int j = 0; j < 4; j++) o16[j] = (short)f2bf(o[j]);
                    *(short4v*)&((u16*)outp)[(size_t)grow * NC + ct * 16 + cbase] = o16;
                } else {
                    *(f32x4*)&((float*)outp)[(size_t)grow * NC + ct * 16 + cbase] = o;
                }
            }
        }
    } else {
        float v[CT * 4];
#pragma unroll
        for (int ct = 0; ct < CT; ct++) {
            const float4 bv = *(const float4*)&bias[ct * 16 + cbase];
            v[ct * 4 + 0] = acc[ct][0] + bv.x;
            v[ct * 4 + 1] = acc[ct][1] + bv.y;
            v[ct * 4 + 2] = acc[ct][2] + bv.z;
            v[ct * 4 + 3] = acc[ct][3] + bv.w;
        }
        float m = v[0];
#pragma unroll
        for (int j = 1; j < CT * 4; j++) m = fmaxf(m, v[j]);
        m = fmaxf(m, __shfl_xor(m, 16));
        m = fmaxf(m, __shfl_xor(m, 32));
        float s = 0.f;
#pragma unroll
        for (int j = 0; j < CT * 4; j++) s += __expf(v[j] - m);
        s += __shfl_xor(s, 16);
        s += __shfl_xor(s, 32);
        const float lg = m + __logf(s);
        if (grow < M) {
#pragma unroll
            for (int ct = 0; ct < CT; ct++) {
                f32x4 o;
#pragma unroll
                for (int j = 0; j < 4; j++) o[j] = v[ct * 4 + j] - lg;
                *(f32x4*)&((float*)outp)[(size_t)grow * NC + ct * 16 + cbase] = o;
            }
        }
    }
}

// ---------------------------------------------------------------------------
// FUSED mgemm2+mgemm3: p2 = ( relu(BN(s1)) @ w1b + b1b, relu ) @ w2a
// Stage1: BN+ReLU staged s1 -> MFMA (128->128) -> +b1b, relu -> bf16 h1 tile
// kept in LDS (granule-XOR swizzled, conflict-free). Stage2: h1 @ w2a
// (128->64) -> p2 bf16. h1 never touches global memory.
// LDS: Asl 16KB (s1 frags, then h1 tile) + Bsl 32KB (w1b frags; first 16KB
// reused for w2a frags) + scb/shb 1KB = 49KB -> 3 blocks/CU.
// ---------------------------------------------------------------------------
__global__ __launch_bounds__(256) void mgemm23_k(
    const u16* __restrict__ s1, const short* __restrict__ w1bf,
    const short* __restrict__ w2af,
    const float* __restrict__ sum, const float* __restrict__ sumsq,
    const float* __restrict__ g, const float* __restrict__ be, float invN,
    const float* __restrict__ b1b, u16* __restrict__ p2, int M)
{
    constexpr int BM = 64, KD = 128, NC = 128, NO = 64;
    constexpr int KC = KD / 32;       // 4
    constexpr int CT = NC / 16;       // 8
    constexpr int CT2 = NO / 16;      // 4
    constexpr int KQ = KD / 4;        // 32
    __shared__ short Asl[BM * KD];    // 16 KB: s1 frags, then h1 tile
    __shared__ short Bsl[NC * KD];    // 32 KB: w1b frags; [0,16KB) reused w2a
    __shared__ float scb[KD];
    __shared__ float shb[KD];

    const int t = threadIdx.x;
    const int l = t & 63;
    const int w = t >> 6;

    // BN affine from stats
    if (t < KD) {
        const float m = sum[t] * invN;
        const float v = sumsq[t] * invN - m * m;
        const float r = rsqrtf(v + 1e-5f);
        const float s = g[t] * r;
        scb[t] = s;
        shb[t] = be[t] - m * s;
    }
    __syncthreads();

    // stage B1 = w1b frags (32KB linear)
    {
        const float4* src = (const float4*)w1bf;
        float4* dst = (float4*)Bsl;
#pragma unroll
        for (int u = t; u < NC * KD / 8; u += 256) dst[u] = src[u];
    }
    // stage A = BN+ReLU(s1) frags
    {
        const int r = t >> 2;
        const int q = t & 3;
        const int grow = blockIdx.x * BM + r;
        const int rt = r >> 4;
        u16 hv[KQ];
        if (grow < M) {
            const u16* ap = s1 + (size_t)grow * KD + q * KQ;
#pragma unroll
            for (int i = 0; i < KQ / 8; i++)
                *(short8*)&hv[i * 8] = ((const short8*)ap)[i];
#pragma unroll
            for (int i = 0; i < KQ; i++) {
                const int k = q * KQ + i;
                hv[i] = f2bf(fmaxf(0.f, bf2f(hv[i]) * scb[k] + shb[k]));
            }
        } else {
#pragma unroll
            for (int i = 0; i < KQ; i++) hv[i] = 0;
        }
#pragma unroll
        for (int gg = 0; gg < KQ / 8; gg++) {
            const int k0 = q * KQ + gg * 8;
            const int kc = k0 >> 5;
            const int lane = (r & 15) + ((k0 >> 3) & 3) * 16;
            *(short8*)&Asl[((rt * KC + kc) * 64 + lane) * 8] =
                *(short8*)&hv[gg * 8];
        }
    }
    __syncthreads();

    // ---- MFMA stage 1: 128 -> 128 ----
    f32x4 acc[CT];
#pragma unroll
    for (int c = 0; c < CT; c++) acc[c] = (f32x4){0.f, 0.f, 0.f, 0.f};
#pragma unroll
    for (int kc = 0; kc < KC; kc++) {
        const short8 x0 = *(const short8*)&Asl[((w * KC + kc) * 64 + l) * 8];
#pragma unroll
        for (int ct = 0; ct < CT; ct++) {
            const short8 wb = *(const short8*)&Bsl[((ct * KC + kc) * 64 + l) * 8];
            acc[ct] = __builtin_amdgcn_mfma_f32_16x16x32_bf16(wb, x0, acc[ct], 0, 0, 0);
        }
    }
    __syncthreads();   // all waves done reading Asl/Bsl

    // ---- h1 tile -> Asl (row-major [64][128] bf16, granule-XOR swizzle) ----
    // granule = col/4 (0..31); swizzled g' = g ^ ((row&7)<<1): writes spread
    // over 8 bank-pairs (2-way = free); 16B reads stay contiguous.
    {
        const int row = w * 16 + (l & 15);
        const int cb4 = l >> 4;        // granule sub-index from lane
        const int sw = (row & 7) << 1;
#pragma unroll
        for (int ct = 0; ct < CT; ct++) {
            const float4 bv = *(const float4*)&b1b[ct * 16 + cb4 * 4];
            short4v o16;
            o16[0] = (short)f2bf(fmaxf(acc[ct][0] + bv.x, 0.f));
            o16[1] = (short)f2bf(fmaxf(acc[ct][1] + bv.y, 0.f));
            o16[2] = (short)f2bf(fmaxf(acc[ct][2] + bv.z, 0.f));
            o16[3] = (short)f2bf(fmaxf(acc[ct][3] + bv.w, 0.f));
            const int gsw = (ct * 4 + cb4) ^ sw;
            *(short4v*)&Asl[row * 128 + gsw * 4] = o16;
        }
    }
    // stage B2 = w2a frags (16KB) into the front of Bsl
    {
        const float4* src = (const float4*)w2af;
        float4* dst = (float4*)Bsl;
#pragma unroll
        for (int u = t; u < NO * KD / 8; u += 256) dst[u] = src[u];
    }
    __syncthreads();

    // ---- MFMA stage 2: 128 -> 64 ----
    f32x4 acc2[CT2];
#pragma unroll
    for (int c = 0; c < CT2; c++) acc2[c] = (f32x4){0.f, 0.f, 0.f, 0.f};
#pragma unroll
    for (int kc = 0; kc < KC; kc++) {
        const int row = w * 16 + (l & 15);
        const int G = kc * 8 + (l >> 4) * 2;           // even granule base
        const int Gs = G ^ ((row & 7) << 1);           // stays even
        const short8 x0 = *(const short8*)&Asl[row * 128 + Gs * 4];
#pragma unroll
        for (int ct = 0; ct < CT2; ct++) {
            const short8 wb = *(const short8*)&Bsl[((ct * KC + kc) * 64 + l) * 8];
            acc2[ct] = __builtin_amdgcn_mfma_f32_16x16x32_bf16(wb, x0, acc2[ct], 0, 0, 0);
        }
    }

    // ---- epilogue: p2 bf16 (no bias: b2a cancels in BN; no relu) ----
    {
        const int cbase = (l >> 4) * 4;
        const int grow = blockIdx.x * BM + w * 16 + (l & 15);
        if (grow < M) {
#pragma unroll
            for (int ct = 0; ct < CT2; ct++) {
                short4v o16;
#pragma unroll
                for (int j = 0; j < 4; j++) o16[j] = (short)f2bf(acc2[ct][j]);
                *(short4v*)&p2[(size_t)grow * NO + ct * 16 + cbase] = o16;
            }
        }
    }
}

// ---------------------------------------------------------------------------
// CSR build: histogram, 3-kernel parallel exclusive scan, bucket fill.
// ---------------------------------------------------------------------------
__global__ __launch_bounds__(256) void hist_k(const int* __restrict__ ei,
                                              int* __restrict__ cnt, int E)
{
    const int gid = blockIdx.x * blockDim.x + threadIdx.x;
    const int stride = gridDim.x * blockDim.x;
    for (int e = gid; e < E; e += stride) atomicAdd(&cnt[ei[E + e]], 1);
}

__global__ __launch_bounds__(256) void bsum_k(const int* __restrict__ cnt,
                                              int* __restrict__ bsum, int N)
{
    __shared__ int ws[4];
    const int i = blockIdx.x * 256 + threadIdx.x;
    int v = (i < N) ? cnt[i] : 0;
    for (int d = 32; d; d >>= 1) v += __shfl_xor(v, d, 64);
    if ((threadIdx.x & 63) == 0) ws[threadIdx.x >> 6] = v;
    __syncthreads();
    if (threadIdx.x == 0) bsum[blockIdx.x] = ws[0] + ws[1] + ws[2] + ws[3];
}

__global__ __launch_bounds__(256) void bscan_k(const int* __restrict__ bsum,
                                               int* __restrict__ bpre, int G1)
{
    __shared__ int part[256];
    const int t = threadIdx.x;
    const int v = (t < G1) ? bsum[t] : 0;
    part[t] = v;
    __syncthreads();
    for (int d = 1; d < 256; d <<= 1) {
        const int u = (t >= d) ? part[t - d] : 0;
        __syncthreads();
        part[t] += u;
        __syncthreads();
    }
    bpre[t] = part[t] - v;   // exclusive
}

__global__ __launch_bounds__(256) void offs_k(const int* __restrict__ cnt,
                                              const int* __restrict__ bpre,
                                              int* __restrict__ off,
                                              int* __restrict__ cursor,
                                              int N, int E)
{
    __shared__ int part[256];
    const int t = threadIdx.x;
    const int i = blockIdx.x * 256 + t;
    const int v = (i < N) ? cnt[i] : 0;
    part[t] = v;
    __syncthreads();
    for (int d = 1; d < 256; d <<= 1) {
        const int u = (t >= d) ? part[t - d] : 0;
        __syncthreads();
        part[t] += u;
        __syncthreads();
    }
    if (i < N) {
        const int o = bpre[blockIdx.x] + part[t] - v;
        off[i] = o;
        cursor[i] = o;
    }
    if (blockIdx.x == 0 && t == 0) off[N] = E;
}

__global__ __launch_bounds__(256) void fill_k(const int* __restrict__ ei,
                                              int* __restrict__ cursor,
                                              int* __restrict__ srcs, int E)
{
    const int gid = blockIdx.x * blockDim.x + threadIdx.x;
    const int stride = gridDim.x * blockDim.x;
    for (int e = gid; e < E; e += stride) {
        const int s = ei[e];
        const int d = ei[E + e];
        const int pos = atomicAdd(&cursor[d], 1);
        srcs[pos] = s;
    }
}

// ---------------------------------------------------------------------------
// Gather segment-sum (bf16 in/out) + fused column stats.  [R5 measured-best,
// BLKN=4 so the grid fills 8+ blocks/CU]
// ---------------------------------------------------------------------------
template <int C>
__global__ __launch_bounds__(256) void segsum_bf(
    const u16* __restrict__ p, const int* __restrict__ off,
    const int* __restrict__ srcs, u16* __restrict__ out,
    float* __restrict__ sum, float* __restrict__ sumsq, int N)
{
    constexpr int BLKN = 4;            // nodes per wave
    constexpr int VPL = C / 64;        // channels per lane (2 or 1)
    __shared__ float red[4][64][2 * VPL];

    const int wv = threadIdx.x >> 6;
    const int l  = threadIdx.x & 63;
    const int base = blockIdx.x * 4 * BLKN;

    float ss[VPL], qq[VPL];
#pragma unroll
    for (int v = 0; v < VPL; v++) { ss[v] = 0.f; qq[v] = 0.f; }

    for (int i = 0; i < BLKN; i++) {
        const int n = base + i * 4 + wv;
        if (n < N) {
            const int lo = __builtin_amdgcn_readfirstlane(off[n]);
            const int hi = __builtin_amdgcn_readfirstlane(off[n + 1]);
            float acc[VPL];
            if constexpr (VPL == 2) {
                const u32 u = *(const u32*)&p[(size_t)n * C + 2 * l];
                acc[0] = bf2f((u16)u);
                acc[1] = bf2f((u16)(u >> 16));
            } else {
                acc[0] = bf2f(p[(size_t)n * C + l]);
            }
            const int cnt = hi - lo;
            if (cnt > 0) {
                const int last = hi - 1;
                int idx[8];
#pragma unroll
                for (int j = 0; j < 8; j++) idx[j] = srcs[min(lo + j, last)];
                for (int e = lo; e < hi; e += 8) {
                    int nx[8];
#pragma unroll
                    for (int j = 0; j < 8; j++)
                        nx[j] = srcs[min(e + 8 + j, last)];   // prefetch next
#pragma unroll
                    for (int j = 0; j < 8; j++) {
                        const bool live = (e + j) < hi;
                        if constexpr (VPL == 2) {
                            const u32 u = *(const u32*)&p[(size_t)idx[j] * C + 2 * l];
                            const float v0 = bf2f((u16)u);
                            const float v1 = bf2f((u16)(u >> 16));
                            acc[0] += live ? v0 : 0.f;
                            acc[1] += live ? v1 : 0.f;
                        } else {
                            const float v = bf2f(p[(size_t)idx[j] * C + l]);
                            acc[0] += live ? v : 0.f;
                        }
                    }
#pragma unroll
                    for (int j = 0; j < 8; j++) idx[j] = nx[j];
                }
            }
            if constexpr (VPL == 2) {
                const u16 r0 = f2bf(acc[0]);
                const u16 r1 = f2bf(acc[1]);
                *(u32*)&out[(size_t)n * C + 2 * l] = (u32)r0 | ((u32)r1 << 16);
                const float f0 = bf2f(r0), f1 = bf2f(r1);
                ss[0] += f0; qq[0] += f0 * f0;
                ss[1] += f1; qq[1] += f1 * f1;
            } else {
                const u16 r = f2bf(acc[0]);
                out[(size_t)n * C + l] = r;
                const float f = bf2f(r);
                ss[0] += f; qq[0] += f * f;
            }
        }
    }

#pragma unroll
    for (int v = 0; v < VPL; v++) {
        red[wv][l][2 * v] = ss[v];
        red[wv][l][2 * v + 1] = qq[v];
    }
    __syncthreads();
    if (wv == 0) {
#pragma unroll
        for (int v = 0; v < VPL; v++) {
            float a = 0.f, b = 0.f;
#pragma unroll
            for (int w2 = 0; w2 < 4; w2++) {
                a += red[w2][l][2 * v];
                b += red[w2][l][2 * v + 1];
            }
            const int ch = (VPL == 2) ? (2 * l + v) : l;
            atomAddF(&sum[ch], a);
            atomAddF(&sumsq[ch], b);
        }
    }
}

extern "C" void kernel_launch(void* const* d_in, const int* in_sizes, int n_in,
                              void* d_out, int out_size, void* d_ws, size_t ws_size,
                              hipStream_t stream)
{
    const float* x   = (const float*)d_in[0];
    const int*   ei  = (const int*)d_in[1];
    const float* w1a = (const float*)d_in[2];
    // d_in[3] = b1a: cancelled by BN
    const float* g1  = (const float*)d_in[4];
    const float* be1 = (const float*)d_in[5];
    const float* w1b = (const float*)d_in[6];
    const float* b1b = (const float*)d_in[7];
    const float* w2a = (const float*)d_in[8];
    // d_in[9] = b2a: cancelled by BN
    const float* g2  = (const float*)d_in[10];
    const float* be2 = (const float*)d_in[11];
    const float* w2b = (const float*)d_in[12];
    const float* b2b = (const float*)d_in[13];
    float* out = (float*)d_out;

    const int N = in_sizes[0] / 128;   // 50000
    const int E = in_sizes[1] / 2;     // 800000

    // ---- workspace layout ----
    u16* buf1 = (u16*)d_ws;                      // N*128 bf16 : p1, then p2
    u16* buf2 = buf1 + (size_t)N * 128;          // N*128 bf16 : s1, then s2
    float* stats = (float*)(buf2 + (size_t)N * 128);  // 1024 floats
    float* sum1 = stats,       *sq1 = stats + 128;
    float* sum2 = stats + 256, *sq2 = stats + 320;
    int* cnt    = (int*)(stats + 1024);          // N
    int* off    = cnt + N;                       // N+1
    int* cursor = off + N + 1;                   // N
    int* srcs   = cursor + N;                    // E
    int* bsum   = srcs + E;                      // 256
    int* bpre   = bsum + 256;                    // 256
    short* w1af = (short*)(bpre + 256);          // 128*128
    short* w1bf = w1af + 128 * 128;              // 128*128
    short* w2af = w1bf + 128 * 128;              // 128*64
    short* w2bf = w2af + 128 * 64;               // 64*64
    u16* p1 = buf1;
    u16* s1 = buf2;
    u16* p2 = buf1;                    // reuse: p1 dead after segsum1
    u16* s2 = buf2;                    // reuse: s1 dead after mgemm23

    hipMemsetAsync(stats, 0, 1024 * sizeof(float) + (size_t)N * sizeof(int), stream);

    const int G1 = (N + 255) / 256;
    const int gb = (N + 63) / 64;      // BM=64 -> 782 blocks
    const int gs = (N + 15) / 16;      // segsum: 4 waves x 4 nodes per block
    const float invN = 1.f / N;

    // ---- CSR build ----
    hist_k<<<1024, 256, 0, stream>>>(ei, cnt, E);
    bsum_k<<<G1, 256, 0, stream>>>(cnt, bsum, N);
    bscan_k<<<1, 256, 0, stream>>>(bsum, bpre, G1);
    offs_k<<<G1, 256, 0, stream>>>(cnt, bpre, off, cursor, N, E);
    fill_k<<<1024, 256, 0, stream>>>(ei, cursor, srcs, E);

    // ---- weight prep (one launch for all four) ----
    wprep4_k<<<22, 256, 0, stream>>>(w1a, w1b, w2a, w2b, w1af, w1bf, w2af, w2bf);

    // ---- Layer 1 ----
    mgemm<128, 128, false, false, false, false, false, true>
        <<<gb, 256, 0, stream>>>(x, w1af, nullptr, nullptr, nullptr, nullptr,
                                 0.f, nullptr, p1, N);
    segsum_bf<128><<<gs, 256, 0, stream>>>(p1, off, srcs, s1, sum1, sq1, N);

    // ---- Fused: h1 = relu(BN(s1)@w1b+b1b); p2 = h1@w2a ----
    mgemm23_k<<<gb, 256, 0, stream>>>(s1, w1bf, w2af, sum1, sq1, g1, be1,
                                      invN, b1b, p2, N);

    // ---- Layer 2 aggregation + output ----
    segsum_bf<64><<<gs, 256, 0, stream>>>(p2, off, srcs, s2, sum2, sq2, N);
    mgemm<64, 64, true, true, true, false, true, false>
        <<<gb, 256, 0, stream>>>(s2, w2bf, sum2, sq2, g2, be2, invN, b2b, out, N);
}

// Round 15
// 300.868 us; speedup vs baseline: 1.3735x; 1.3130x over previous
//
#include <hip/hip_runtime.h>

// ---------------------------------------------------------------------------
// GIN 2-layer forward (bf16 features, MFMA GEMMs, CSR gather segment-sum):
//   CSR bucket edges by dst (hist -> parallel scan -> fill)
//   p1 = bf16( x @ w1a )                      [b1a cancels in BN]
//   s1 = bf16( p1[n] + gather-sum )           (fused column stats)
//   p2 = bf16( relu(BN(s1)) @ w1b + b1b, relu ) @ w2a   [FUSED mgemm23]
//   s2 = bf16( p2[n] + gather-sum )
//   out = log_softmax( relu(BN(s2)) @ w2b + b2b )  fp32, fused epilogue
// R14 = R13's fused-GEMM structure + R5's measured-best segsum (BLKN=8;
// R13's BLKN=4 regressed 96->162us: the gather has an occupancy sweet spot
// at ~37% -- more streams/CU thrash L1/MSHR).
// ---------------------------------------------------------------------------

typedef unsigned short u16;
typedef unsigned int u32;
typedef __attribute__((ext_vector_type(8))) short short8;
typedef __attribute__((ext_vector_type(4))) short short4v;
typedef __attribute__((ext_vector_type(4))) float f32x4;

#define DEV_INLINE __device__ __forceinline__

DEV_INLINE void atomAddF(float* p, float v) { unsafeAtomicAdd(p, v); }

DEV_INLINE u16 f2bf(float f) {
    unsigned u = __float_as_uint(f);
    u += 0x7fffu + ((u >> 16) & 1u);   // round-to-nearest-even
    return (u16)(u >> 16);
}
DEV_INLINE float bf2f(u16 h) { return __uint_as_float(((unsigned)h) << 16); }

// ---------------------------------------------------------------------------
// Weight prep (all 4 weights, one launch): W[K][NOUT] fp32 -> frag-ordered
// bf16 (MFMA A-operand, swapped). unit=(ct,kc,lane): 8 bf16 for
// col=ct*16+(lane&15), k=kc*32+(lane>>4)*8+j.
// ---------------------------------------------------------------------------
__global__ __launch_bounds__(256) void wprep4_k(
    const float* __restrict__ w1a, const float* __restrict__ w1b,
    const float* __restrict__ w2a, const float* __restrict__ w2b,
    short* __restrict__ o1a, short* __restrict__ o1b,
    short* __restrict__ o2a, short* __restrict__ o2b)
{
    int b = blockIdx.x;
    const float* W; short* wf; int K, NOUT;
    if (b < 8)       { W = w1a; wf = o1a; K = 128; NOUT = 128; }
    else if (b < 16) { W = w1b; wf = o1b; K = 128; NOUT = 128; b -= 8; }
    else if (b < 20) { W = w2a; wf = o2a; K = 128; NOUT = 64;  b -= 16; }
    else             { W = w2b; wf = o2b; K = 64;  NOUT = 64;  b -= 20; }
    const int u = b * 256 + threadIdx.x;
    const int units = (NOUT / 16) * (K / 32) * 64;
    if (u >= units) return;
    const int per_ct = (K / 32) * 64;
    const int ct = u / per_ct;
    const int rem = u % per_ct;
    const int kc = rem >> 6;
    const int l = rem & 63;
    const int col = ct * 16 + (l & 15);
    const int k0 = kc * 32 + (l >> 4) * 8;
    short8 pk;
#pragma unroll
    for (int j = 0; j < 8; j++)
        pk[j] = (short)f2bf(W[(size_t)(k0 + j) * NOUT + col]);
    *(short8*)&wf[(size_t)u * 8] = pk;
}

// ---------------------------------------------------------------------------
// MFMA GEMM, BM=64 rows/block: out[M][NC] = f(A[M][KD]) @ W
// f = identity or BN+ReLU with sc/sh computed IN-KERNEL from sum/sumsq.
// ---------------------------------------------------------------------------
template <int KD, int NC, bool ABF16, bool BNIN, bool BIAS, bool RELUOUT,
          bool LOGSM, bool OBF16>
__global__ __launch_bounds__(256) void mgemm(
    const void* __restrict__ Ap, const short* __restrict__ Wf,
    const float* __restrict__ sum, const float* __restrict__ sumsq,
    const float* __restrict__ g, const float* __restrict__ be, float invN,
    const float* __restrict__ bias, void* __restrict__ outp, int M)
{
    constexpr int BM = 64;
    constexpr int KC = KD / 32;
    constexpr int CT = NC / 16;
    constexpr int KQ = KD / 4;
    __shared__ short Asl[BM * KD];
    __shared__ short Bsl[NC * KD];
    __shared__ float scb[BNIN ? KD : 1];
    __shared__ float shb[BNIN ? KD : 1];

    const int t = threadIdx.x;
    const int l = t & 63;
    const int w = t >> 6;

    if constexpr (BNIN) {
        if (t < KD) {
            const float m = sum[t] * invN;
            const float v = sumsq[t] * invN - m * m;
            const float r = rsqrtf(v + 1e-5f);
            const float s = g[t] * r;
            scb[t] = s;
            shb[t] = be[t] - m * s;
        }
        __syncthreads();
    }

    {
        const float4* src = (const float4*)Wf;
        float4* dst = (float4*)Bsl;
        constexpr int NU = NC * KD / 8;
#pragma unroll
        for (int u = t; u < NU; u += 256) dst[u] = src[u];
    }
    {
        const int r = t >> 2;
        const int q = t & 3;
        const int grow = blockIdx.x * BM + r;
        const int rt = r >> 4;
        u16 hv[KQ];
        if (grow < M) {
            if constexpr (ABF16) {
                const u16* ap = (const u16*)Ap + (size_t)grow * KD + q * KQ;
#pragma unroll
                for (int i = 0; i < KQ / 8; i++)
                    *(short8*)&hv[i * 8] = ((const short8*)ap)[i];
                if constexpr (BNIN) {
#pragma unroll
                    for (int i = 0; i < KQ; i++) {
                        const int k = q * KQ + i;
                        hv[i] = f2bf(fmaxf(0.f, bf2f(hv[i]) * scb[k] + shb[k]));
                    }
                }
            } else {
                const float* ap = (const float*)Ap + (size_t)grow * KD + q * KQ;
#pragma unroll
                for (int i = 0; i < KQ / 4; i++) {
                    const float4 v = ((const float4*)ap)[i];
                    float f0 = v.x, f1 = v.y, f2 = v.z, f3 = v.w;
                    if constexpr (BNIN) {
                        const int k = q * KQ + i * 4;
                        f0 = fmaxf(0.f, f0 * scb[k + 0] + shb[k + 0]);
                        f1 = fmaxf(0.f, f1 * scb[k + 1] + shb[k + 1]);
                        f2 = fmaxf(0.f, f2 * scb[k + 2] + shb[k + 2]);
                        f3 = fmaxf(0.f, f3 * scb[k + 3] + shb[k + 3]);
                    }
                    hv[i * 4 + 0] = f2bf(f0); hv[i * 4 + 1] = f2bf(f1);
                    hv[i * 4 + 2] = f2bf(f2); hv[i * 4 + 3] = f2bf(f3);
                }
            }
        } else {
#pragma unroll
            for (int i = 0; i < KQ; i++) hv[i] = 0;
        }
#pragma unroll
        for (int gg = 0; gg < KQ / 8; gg++) {
            const int k0 = q * KQ + gg * 8;
            const int kc = k0 >> 5;
            const int lane = (r & 15) + ((k0 >> 3) & 3) * 16;
            *(short8*)&Asl[((rt * KC + kc) * 64 + lane) * 8] =
                *(short8*)&hv[gg * 8];
        }
    }
    __syncthreads();

    f32x4 acc[CT];
#pragma unroll
    for (int c = 0; c < CT; c++) acc[c] = (f32x4){0.f, 0.f, 0.f, 0.f};

#pragma unroll
    for (int kc = 0; kc < KC; kc++) {
        const short8 x0 = *(const short8*)&Asl[((w * KC + kc) * 64 + l) * 8];
#pragma unroll
        for (int ct = 0; ct < CT; ct++) {
            const short8 wb = *(const short8*)&Bsl[((ct * KC + kc) * 64 + l) * 8];
            acc[ct] = __builtin_amdgcn_mfma_f32_16x16x32_bf16(wb, x0, acc[ct], 0, 0, 0);
        }
    }

    const int cbase = (l >> 4) * 4;
    const int grow = blockIdx.x * BM + w * 16 + (l & 15);
    if constexpr (!LOGSM) {
        if (grow < M) {
#pragma unroll
            for (int ct = 0; ct < CT; ct++) {
                f32x4 o = acc[ct];
                if constexpr (BIAS) {
                    const float4 bv = *(const float4*)&bias[ct * 16 + cbase];
                    o[0] += bv.x; o[1] += bv.y; o[2] += bv.z; o[3] += bv.w;
                }
                if constexpr (RELUOUT) {
#pragma unroll
                    for (int j = 0; j < 4; j++) o[j] = fmaxf(o[j], 0.f);
                }
                if constexpr (OBF16) {
                    short4v o16;
#pragma unroll
                    for (int j = 0; j < 4; j++) o16[j] = (short)f2bf(o[j]);
                    *(short4v*)&((u16*)outp)[(size_t)grow * NC + ct * 16 + cbase] = o16;
                } else {
                    *(f32x4*)&((float*)outp)[(size_t)grow * NC + ct * 16 + cbase] = o;
                }
            }
        }
    } else {
        float v[CT * 4];
#pragma unroll
        for (int ct = 0; ct < CT; ct++) {
            const float4 bv = *(const float4*)&bias[ct * 16 + cbase];
            v[ct * 4 + 0] = acc[ct][0] + bv.x;
            v[ct * 4 + 1] = acc[ct][1] + bv.y;
            v[ct * 4 + 2] = acc[ct][2] + bv.z;
            v[ct * 4 + 3] = acc[ct][3] + bv.w;
        }
        float m = v[0];
#pragma unroll
        for (int j = 1; j < CT * 4; j++) m = fmaxf(m, v[j]);
        m = fmaxf(m, __shfl_xor(m, 16));
        m = fmaxf(m, __shfl_xor(m, 32));
        float s = 0.f;
#pragma unroll
        for (int j = 0; j < CT * 4; j++) s += __expf(v[j] - m);
        s += __shfl_xor(s, 16);
        s += __shfl_xor(s, 32);
        const float lg = m + __logf(s);
        if (grow < M) {
#pragma unroll
            for (int ct = 0; ct < CT; ct++) {
                f32x4 o;
#pragma unroll
                for (int j = 0; j < 4; j++) o[j] = v[ct * 4 + j] - lg;
                *(f32x4*)&((float*)outp)[(size_t)grow * NC + ct * 16 + cbase] = o;
            }
        }
    }
}

// ---------------------------------------------------------------------------
// FUSED mgemm2+mgemm3: p2 = ( relu(BN(s1)) @ w1b + b1b, relu ) @ w2a
// h1 lives only in registers/LDS (granule-XOR swizzled tile).
// ---------------------------------------------------------------------------
__global__ __launch_bounds__(256) void mgemm23_k(
    const u16* __restrict__ s1, const short* __restrict__ w1bf,
    const short* __restrict__ w2af,
    const float* __restrict__ sum, const float* __restrict__ sumsq,
    const float* __restrict__ g, const float* __restrict__ be, float invN,
    const float* __restrict__ b1b, u16* __restrict__ p2, int M)
{
    constexpr int BM = 64, KD = 128, NC = 128, NO = 64;
    constexpr int KC = KD / 32;       // 4
    constexpr int CT = NC / 16;       // 8
    constexpr int CT2 = NO / 16;      // 4
    constexpr int KQ = KD / 4;        // 32
    __shared__ short Asl[BM * KD];    // 16 KB: s1 frags, then h1 tile
    __shared__ short Bsl[NC * KD];    // 32 KB: w1b frags; [0,16KB) reused w2a
    __shared__ float scb[KD];
    __shared__ float shb[KD];

    const int t = threadIdx.x;
    const int l = t & 63;
    const int w = t >> 6;

    if (t < KD) {
        const float m = sum[t] * invN;
        const float v = sumsq[t] * invN - m * m;
        const float r = rsqrtf(v + 1e-5f);
        const float s = g[t] * r;
        scb[t] = s;
        shb[t] = be[t] - m * s;
    }
    __syncthreads();

    {
        const float4* src = (const float4*)w1bf;
        float4* dst = (float4*)Bsl;
#pragma unroll
        for (int u = t; u < NC * KD / 8; u += 256) dst[u] = src[u];
    }
    {
        const int r = t >> 2;
        const int q = t & 3;
        const int grow = blockIdx.x * BM + r;
        const int rt = r >> 4;
        u16 hv[KQ];
        if (grow < M) {
            const u16* ap = s1 + (size_t)grow * KD + q * KQ;
#pragma unroll
            for (int i = 0; i < KQ / 8; i++)
                *(short8*)&hv[i * 8] = ((const short8*)ap)[i];
#pragma unroll
            for (int i = 0; i < KQ; i++) {
                const int k = q * KQ + i;
                hv[i] = f2bf(fmaxf(0.f, bf2f(hv[i]) * scb[k] + shb[k]));
            }
        } else {
#pragma unroll
            for (int i = 0; i < KQ; i++) hv[i] = 0;
        }
#pragma unroll
        for (int gg = 0; gg < KQ / 8; gg++) {
            const int k0 = q * KQ + gg * 8;
            const int kc = k0 >> 5;
            const int lane = (r & 15) + ((k0 >> 3) & 3) * 16;
            *(short8*)&Asl[((rt * KC + kc) * 64 + lane) * 8] =
                *(short8*)&hv[gg * 8];
        }
    }
    __syncthreads();

    // ---- MFMA stage 1: 128 -> 128 ----
    f32x4 acc[CT];
#pragma unroll
    for (int c = 0; c < CT; c++) acc[c] = (f32x4){0.f, 0.f, 0.f, 0.f};
#pragma unroll
    for (int kc = 0; kc < KC; kc++) {
        const short8 x0 = *(const short8*)&Asl[((w * KC + kc) * 64 + l) * 8];
#pragma unroll
        for (int ct = 0; ct < CT; ct++) {
            const short8 wb = *(const short8*)&Bsl[((ct * KC + kc) * 64 + l) * 8];
            acc[ct] = __builtin_amdgcn_mfma_f32_16x16x32_bf16(wb, x0, acc[ct], 0, 0, 0);
        }
    }
    __syncthreads();

    // ---- h1 tile -> Asl (row-major [64][128] bf16, granule-XOR swizzle) ----
    {
        const int row = w * 16 + (l & 15);
        const int cb4 = l >> 4;
        const int sw = (row & 7) << 1;
#pragma unroll
        for (int ct = 0; ct < CT; ct++) {
            const float4 bv = *(const float4*)&b1b[ct * 16 + cb4 * 4];
            short4v o16;
            o16[0] = (short)f2bf(fmaxf(acc[ct][0] + bv.x, 0.f));
            o16[1] = (short)f2bf(fmaxf(acc[ct][1] + bv.y, 0.f));
            o16[2] = (short)f2bf(fmaxf(acc[ct][2] + bv.z, 0.f));
            o16[3] = (short)f2bf(fmaxf(acc[ct][3] + bv.w, 0.f));
            const int gsw = (ct * 4 + cb4) ^ sw;
            *(short4v*)&Asl[row * 128 + gsw * 4] = o16;
        }
    }
    {
        const float4* src = (const float4*)w2af;
        float4* dst = (float4*)Bsl;
#pragma unroll
        for (int u = t; u < NO * KD / 8; u += 256) dst[u] = src[u];
    }
    __syncthreads();

    // ---- MFMA stage 2: 128 -> 64 ----
    f32x4 acc2[CT2];
#pragma unroll
    for (int c = 0; c < CT2; c++) acc2[c] = (f32x4){0.f, 0.f, 0.f, 0.f};
#pragma unroll
    for (int kc = 0; kc < KC; kc++) {
        const int row = w * 16 + (l & 15);
        const int G = kc * 8 + (l >> 4) * 2;
        const int Gs = G ^ ((row & 7) << 1);
        const short8 x0 = *(const short8*)&Asl[row * 128 + Gs * 4];
#pragma unroll
        for (int ct = 0; ct < CT2; ct++) {
            const short8 wb = *(const short8*)&Bsl[((ct * KC + kc) * 64 + l) * 8];
            acc2[ct] = __builtin_amdgcn_mfma_f32_16x16x32_bf16(wb, x0, acc2[ct], 0, 0, 0);
        }
    }

    {
        const int cbase = (l >> 4) * 4;
        const int grow = blockIdx.x * BM + w * 16 + (l & 15);
        if (grow < M) {
#pragma unroll
            for (int ct = 0; ct < CT2; ct++) {
                short4v o16;
#pragma unroll
                for (int j = 0; j < 4; j++) o16[j] = (short)f2bf(acc2[ct][j]);
                *(short4v*)&p2[(size_t)grow * NO + ct * 16 + cbase] = o16;
            }
        }
    }
}

// ---------------------------------------------------------------------------
// CSR build: histogram, 3-kernel parallel exclusive scan, bucket fill.
// ---------------------------------------------------------------------------
__global__ __launch_bounds__(256) void hist_k(const int* __restrict__ ei,
                                              int* __restrict__ cnt, int E)
{
    const int gid = blockIdx.x * blockDim.x + threadIdx.x;
    const int stride = gridDim.x * blockDim.x;
    for (int e = gid; e < E; e += stride) atomicAdd(&cnt[ei[E + e]], 1);
}

__global__ __launch_bounds__(256) void bsum_k(const int* __restrict__ cnt,
                                              int* __restrict__ bsum, int N)
{
    __shared__ int ws[4];
    const int i = blockIdx.x * 256 + threadIdx.x;
    int v = (i < N) ? cnt[i] : 0;
    for (int d = 32; d; d >>= 1) v += __shfl_xor(v, d, 64);
    if ((threadIdx.x & 63) == 0) ws[threadIdx.x >> 6] = v;
    __syncthreads();
    if (threadIdx.x == 0) bsum[blockIdx.x] = ws[0] + ws[1] + ws[2] + ws[3];
}

__global__ __launch_bounds__(256) void bscan_k(const int* __restrict__ bsum,
                                               int* __restrict__ bpre, int G1)
{
    __shared__ int part[256];
    const int t = threadIdx.x;
    const int v = (t < G1) ? bsum[t] : 0;
    part[t] = v;
    __syncthreads();
    for (int d = 1; d < 256; d <<= 1) {
        const int u = (t >= d) ? part[t - d] : 0;
        __syncthreads();
        part[t] += u;
        __syncthreads();
    }
    bpre[t] = part[t] - v;   // exclusive
}

__global__ __launch_bounds__(256) void offs_k(const int* __restrict__ cnt,
                                              const int* __restrict__ bpre,
                                              int* __restrict__ off,
                                              int* __restrict__ cursor,
                                              int N, int E)
{
    __shared__ int part[256];
    const int t = threadIdx.x;
    const int i = blockIdx.x * 256 + t;
    const int v = (i < N) ? cnt[i] : 0;
    part[t] = v;
    __syncthreads();
    for (int d = 1; d < 256; d <<= 1) {
        const int u = (t >= d) ? part[t - d] : 0;
        __syncthreads();
        part[t] += u;
        __syncthreads();
    }
    if (i < N) {
        const int o = bpre[blockIdx.x] + part[t] - v;
        off[i] = o;
        cursor[i] = o;
    }
    if (blockIdx.x == 0 && t == 0) off[N] = E;
}

__global__ __launch_bounds__(256) void fill_k(const int* __restrict__ ei,
                                              int* __restrict__ cursor,
                                              int* __restrict__ srcs, int E)
{
    const int gid = blockIdx.x * blockDim.x + threadIdx.x;
    const int stride = gridDim.x * blockDim.x;
    for (int e = gid; e < E; e += stride) {
        const int s = ei[e];
        const int d = ei[E + e];
        const int pos = atomicAdd(&cursor[d], 1);
        srcs[pos] = s;
    }
}

// ---------------------------------------------------------------------------
// Gather segment-sum (bf16 in/out) + fused column stats.  [R5 measured-best:
// BLKN=8, ~37% occupancy sweet spot — do not change]
// ---------------------------------------------------------------------------
template <int C>
__global__ __launch_bounds__(256) void segsum_bf(
    const u16* __restrict__ p, const int* __restrict__ off,
    const int* __restrict__ srcs, u16* __restrict__ out,
    float* __restrict__ sum, float* __restrict__ sumsq, int N)
{
    constexpr int BLKN = 8;            // nodes per wave
    constexpr int VPL = C / 64;        // channels per lane (2 or 1)
    __shared__ float red[4][64][2 * VPL];

    const int wv = threadIdx.x >> 6;
    const int l  = threadIdx.x & 63;
    const int base = blockIdx.x * 4 * BLKN;

    float ss[VPL], qq[VPL];
#pragma unroll
    for (int v = 0; v < VPL; v++) { ss[v] = 0.f; qq[v] = 0.f; }

    for (int i = 0; i < BLKN; i++) {
        const int n = base + i * 4 + wv;
        if (n < N) {
            const int lo = __builtin_amdgcn_readfirstlane(off[n]);
            const int hi = __builtin_amdgcn_readfirstlane(off[n + 1]);
            float acc[VPL];
            if constexpr (VPL == 2) {
                const u32 u = *(const u32*)&p[(size_t)n * C + 2 * l];
                acc[0] = bf2f((u16)u);
                acc[1] = bf2f((u16)(u >> 16));
            } else {
                acc[0] = bf2f(p[(size_t)n * C + l]);
            }
            const int cnt = hi - lo;
            if (cnt > 0) {
                const int last = hi - 1;
                int idx[8];
#pragma unroll
                for (int j = 0; j < 8; j++) idx[j] = srcs[min(lo + j, last)];
                for (int e = lo; e < hi; e += 8) {
                    int nx[8];
#pragma unroll
                    for (int j = 0; j < 8; j++)
                        nx[j] = srcs[min(e + 8 + j, last)];   // prefetch next
#pragma unroll
                    for (int j = 0; j < 8; j++) {
                        const bool live = (e + j) < hi;
                        if constexpr (VPL == 2) {
                            const u32 u = *(const u32*)&p[(size_t)idx[j] * C + 2 * l];
                            const float v0 = bf2f((u16)u);
                            const float v1 = bf2f((u16)(u >> 16));
                            acc[0] += live ? v0 : 0.f;
                            acc[1] += live ? v1 : 0.f;
                        } else {
                            const float v = bf2f(p[(size_t)idx[j] * C + l]);
                            acc[0] += live ? v : 0.f;
                        }
                    }
#pragma unroll
                    for (int j = 0; j < 8; j++) idx[j] = nx[j];
                }
            }
            if constexpr (VPL == 2) {
                const u16 r0 = f2bf(acc[0]);
                const u16 r1 = f2bf(acc[1]);
                *(u32*)&out[(size_t)n * C + 2 * l] = (u32)r0 | ((u32)r1 << 16);
                const float f0 = bf2f(r0), f1 = bf2f(r1);
                ss[0] += f0; qq[0] += f0 * f0;
                ss[1] += f1; qq[1] += f1 * f1;
            } else {
                const u16 r = f2bf(acc[0]);
                out[(size_t)n * C + l] = r;
                const float f = bf2f(r);
                ss[0] += f; qq[0] += f * f;
            }
        }
    }

#pragma unroll
    for (int v = 0; v < VPL; v++) {
        red[wv][l][2 * v] = ss[v];
        red[wv][l][2 * v + 1] = qq[v];
    }
    __syncthreads();
    if (wv == 0) {
#pragma unroll
        for (int v = 0; v < VPL; v++) {
            float a = 0.f, b = 0.f;
#pragma unroll
            for (int w2 = 0; w2 < 4; w2++) {
                a += red[w2][l][2 * v];
                b += red[w2][l][2 * v + 1];
            }
            const int ch = (VPL == 2) ? (2 * l + v) : l;
            atomAddF(&sum[ch], a);
            atomAddF(&sumsq[ch], b);
        }
    }
}

extern "C" void kernel_launch(void* const* d_in, const int* in_sizes, int n_in,
                              void* d_out, int out_size, void* d_ws, size_t ws_size,
                              hipStream_t stream)
{
    const float* x   = (const float*)d_in[0];
    const int*   ei  = (const int*)d_in[1];
    const float* w1a = (const float*)d_in[2];
    // d_in[3] = b1a: cancelled by BN
    const float* g1  = (const float*)d_in[4];
    const float* be1 = (const float*)d_in[5];
    const float* w1b = (const float*)d_in[6];
    const float* b1b = (const float*)d_in[7];
    const float* w2a = (const float*)d_in[8];
    // d_in[9] = b2a: cancelled by BN
    const float* g2  = (const float*)d_in[10];
    const float* be2 = (const float*)d_in[11];
    const float* w2b = (const float*)d_in[12];
    const float* b2b = (const float*)d_in[13];
    float* out = (float*)d_out;

    const int N = in_sizes[0] / 128;   // 50000
    const int E = in_sizes[1] / 2;     // 800000

    // ---- workspace layout ----
    u16* buf1 = (u16*)d_ws;                      // N*128 bf16 : p1, then p2
    u16* buf2 = buf1 + (size_t)N * 128;          // N*128 bf16 : s1, then s2
    float* stats = (float*)(buf2 + (size_t)N * 128);  // 1024 floats
    float* sum1 = stats,       *sq1 = stats + 128;
    float* sum2 = stats + 256, *sq2 = stats + 320;
    int* cnt    = (int*)(stats + 1024);          // N
    int* off    = cnt + N;                       // N+1
    int* cursor = off + N + 1;                   // N
    int* srcs   = cursor + N;                    // E
    int* bsum   = srcs + E;                      // 256
    int* bpre   = bsum + 256;                    // 256
    short* w1af = (short*)(bpre + 256);          // 128*128
    short* w1bf = w1af + 128 * 128;              // 128*128
    short* w2af = w1bf + 128 * 128;              // 128*64
    short* w2bf = w2af + 128 * 64;               // 64*64
    u16* p1 = buf1;
    u16* s1 = buf2;
    u16* p2 = buf1;                    // reuse: p1 dead after segsum1
    u16* s2 = buf2;                    // reuse: s1 dead after mgemm23

    hipMemsetAsync(stats, 0, 1024 * sizeof(float) + (size_t)N * sizeof(int), stream);

    const int G1 = (N + 255) / 256;
    const int gb = (N + 63) / 64;      // BM=64 -> 782 blocks
    const int gs = (N + 31) / 32;      // segsum: 4 waves x 8 nodes per block
    const float invN = 1.f / N;

    // ---- CSR build ----
    hist_k<<<1024, 256, 0, stream>>>(ei, cnt, E);
    bsum_k<<<G1, 256, 0, stream>>>(cnt, bsum, N);
    bscan_k<<<1, 256, 0, stream>>>(bsum, bpre, G1);
    offs_k<<<G1, 256, 0, stream>>>(cnt, bpre, off, cursor, N, E);
    fill_k<<<1024, 256, 0, stream>>>(ei, cursor, srcs, E);

    // ---- weight prep (one launch for all four) ----
    wprep4_k<<<22, 256, 0, stream>>>(w1a, w1b, w2a, w2b, w1af, w1bf, w2af, w2bf);

    // ---- Layer 1 ----
    mgemm<128, 128, false, false, false, false, false, true>
        <<<gb, 256, 0, stream>>>(x, w1af, nullptr, nullptr, nullptr, nullptr,
                                 0.f, nullptr, p1, N);
    segsum_bf<128><<<gs, 256, 0, stream>>>(p1, off, srcs, s1, sum1, sq1, N);

    // ---- Fused: h1 = relu(BN(s1)@w1b+b1b); p2 = h1@w2a ----
    mgemm23_k<<<gb, 256, 0, stream>>>(s1, w1bf, w2af, sum1, sq1, g1, be1,
                                      invN, b1b, p2, N);

    // ---- Layer 2 aggregation + output ----
    segsum_bf<64><<<gs, 256, 0, stream>>>(p2, off, srcs, s2, sum2, sq2, N);
    mgemm<64, 64, true, true, true, false, true, false>
        <<<gb, 256, 0, stream>>>(s2, w2bf, sum2, sq2, g2, be2, invN, b2b, out, N);
}

// Round 16
// 290.612 us; speedup vs baseline: 1.4220x; 1.0353x over previous
//
#include <hip/hip_runtime.h>

// ---------------------------------------------------------------------------
// GIN 2-layer forward (bf16 features, MFMA GEMMs, CSR gather segment-sum):
//   CSR bucket edges by dst (hist -> single-kernel scan -> fill)
//   p1 = bf16( x @ w1a )                      [b1a cancels in BN]
//   s1 = bf16( p1[n] + gather-sum )           (fused column stats)
//   p2 = bf16( relu(BN(s1)) @ w1b + b1b, relu ) @ w2a   [FUSED mgemm23]
//   s2 = bf16( p2[n] + gather-sum )
//   out = log_softmax( relu(BN(s2)) @ w2b + b2b )  fp32, fused epilogue
// R15: (1) bsum+bscan+offs -> one scan1_k (publish/poll aggregates; 196
// blocks all co-resident). (2) mgemm1/mgemm23 use per-wave REGISTER B-frags
// (LDS 48KB->16KB, 3->9 blocks/CU) to hide staging latency. segsum untouched
// (R5 structure, at its measured per-CU scattered-transaction wall).
// ---------------------------------------------------------------------------

typedef unsigned short u16;
typedef unsigned int u32;
typedef __attribute__((ext_vector_type(8))) short short8;
typedef __attribute__((ext_vector_type(4))) short short4v;
typedef __attribute__((ext_vector_type(4))) float f32x4;

#define DEV_INLINE __device__ __forceinline__

DEV_INLINE void atomAddF(float* p, float v) { unsafeAtomicAdd(p, v); }

DEV_INLINE u16 f2bf(float f) {
    unsigned u = __float_as_uint(f);
    u += 0x7fffu + ((u >> 16) & 1u);   // round-to-nearest-even
    return (u16)(u >> 16);
}
DEV_INLINE float bf2f(u16 h) { return __uint_as_float(((unsigned)h) << 16); }

// ---------------------------------------------------------------------------
// Weight prep (all 4 weights, one launch): W[K][NOUT] fp32 -> frag-ordered
// bf16. unit=(ct,kc,lane): 8 bf16 for col=ct*16+(lane&15), k=kc*32+(lane>>4)*8+j.
// ---------------------------------------------------------------------------
__global__ __launch_bounds__(256) void wprep4_k(
    const float* __restrict__ w1a, const float* __restrict__ w1b,
    const float* __restrict__ w2a, const float* __restrict__ w2b,
    short* __restrict__ o1a, short* __restrict__ o1b,
    short* __restrict__ o2a, short* __restrict__ o2b)
{
    int b = blockIdx.x;
    const float* W; short* wf; int K, NOUT;
    if (b < 8)       { W = w1a; wf = o1a; K = 128; NOUT = 128; }
    else if (b < 16) { W = w1b; wf = o1b; K = 128; NOUT = 128; b -= 8; }
    else if (b < 20) { W = w2a; wf = o2a; K = 128; NOUT = 64;  b -= 16; }
    else             { W = w2b; wf = o2b; K = 64;  NOUT = 64;  b -= 20; }
    const int u = b * 256 + threadIdx.x;
    const int units = (NOUT / 16) * (K / 32) * 64;
    if (u >= units) return;
    const int per_ct = (K / 32) * 64;
    const int ct = u / per_ct;
    const int rem = u % per_ct;
    const int kc = rem >> 6;
    const int l = rem & 63;
    const int col = ct * 16 + (l & 15);
    const int k0 = kc * 32 + (l >> 4) * 8;
    short8 pk;
#pragma unroll
    for (int j = 0; j < 8; j++)
        pk[j] = (short)f2bf(W[(size_t)(k0 + j) * NOUT + col]);
    *(short8*)&wf[(size_t)u * 8] = pk;
}

// ---------------------------------------------------------------------------
// mgemm1: p1 = bf16( x @ w1a ).  Reg-B structure: wave w holds col-tiles
// {2w,2w+1} in VGPRs; LDS only for the A tile (16KB) -> ~9 blocks/CU.
// ---------------------------------------------------------------------------
__global__ __launch_bounds__(256) void mgemm1_k(
    const float* __restrict__ x, const short* __restrict__ wf,
    u16* __restrict__ p1, int M)
{
    constexpr int KD = 128, NC = 128, KC = 4, KQ = 32;
    __shared__ short Asl[64 * KD];
    const int t = threadIdx.x;
    const int l = t & 63;
    const int w = t >> 6;

    // B frags in registers (coalesced 16B/lane)
    short8 B[2][KC];
#pragma unroll
    for (int c = 0; c < 2; c++)
#pragma unroll
        for (int kc = 0; kc < KC; kc++)
            B[c][kc] = *(const short8*)&wf[(((w * 2 + c) * KC + kc) * 64 + l) * 8];

    // stage A: 4 threads/row, fp32 -> bf16 frags
    {
        const int r = t >> 2;
        const int q = t & 3;
        const int grow = blockIdx.x * 64 + r;
        const int rt = r >> 4;
        u16 hv[KQ];
        if (grow < M) {
            const float* ap = x + (size_t)grow * KD + q * KQ;
#pragma unroll
            for (int i = 0; i < KQ / 4; i++) {
                const float4 v = ((const float4*)ap)[i];
                hv[i * 4 + 0] = f2bf(v.x); hv[i * 4 + 1] = f2bf(v.y);
                hv[i * 4 + 2] = f2bf(v.z); hv[i * 4 + 3] = f2bf(v.w);
            }
        } else {
#pragma unroll
            for (int i = 0; i < KQ; i++) hv[i] = 0;
        }
#pragma unroll
        for (int gg = 0; gg < KQ / 8; gg++) {
            const int k0 = q * KQ + gg * 8;
            const int kc = k0 >> 5;
            const int lane = (r & 15) + ((k0 >> 3) & 3) * 16;
            *(short8*)&Asl[((rt * KC + kc) * 64 + lane) * 8] = *(short8*)&hv[gg * 8];
        }
    }
    __syncthreads();

    f32x4 acc[4][2];
#pragma unroll
    for (int rt = 0; rt < 4; rt++)
#pragma unroll
        for (int c = 0; c < 2; c++) acc[rt][c] = (f32x4){0.f, 0.f, 0.f, 0.f};

#pragma unroll
    for (int kc = 0; kc < KC; kc++)
#pragma unroll
        for (int rt = 0; rt < 4; rt++) {
            const short8 x0 = *(const short8*)&Asl[((rt * KC + kc) * 64 + l) * 8];
            acc[rt][0] = __builtin_amdgcn_mfma_f32_16x16x32_bf16(B[0][kc], x0, acc[rt][0], 0, 0, 0);
            acc[rt][1] = __builtin_amdgcn_mfma_f32_16x16x32_bf16(B[1][kc], x0, acc[rt][1], 0, 0, 0);
        }

    const int cbase = (l >> 4) * 4;
#pragma unroll
    for (int rt = 0; rt < 4; rt++) {
        const int grow = blockIdx.x * 64 + rt * 16 + (l & 15);
        if (grow < M) {
#pragma unroll
            for (int c = 0; c < 2; c++) {
                short4v o16;
#pragma unroll
                for (int j = 0; j < 4; j++) o16[j] = (short)f2bf(acc[rt][c][j]);
                *(short4v*)&p1[(size_t)grow * NC + (w * 2 + c) * 16 + cbase] = o16;
            }
        }
    }
}

// ---------------------------------------------------------------------------
// FUSED mgemm23 (reg-B both stages): p2 = (relu(BN(s1))@w1b+b1b, relu) @ w2a
// LDS: Asl 16KB (s1 frags, then h1 swizzled tile) + scb/shb -> ~9 blocks/CU.
// ---------------------------------------------------------------------------
__global__ __launch_bounds__(256) void mgemm23_k(
    const u16* __restrict__ s1, const short* __restrict__ w1bf,
    const short* __restrict__ w2af,
    const float* __restrict__ sum, const float* __restrict__ sumsq,
    const float* __restrict__ g, const float* __restrict__ be, float invN,
    const float* __restrict__ b1b, u16* __restrict__ p2, int M)
{
    constexpr int KD = 128, NC = 128, NO = 64, KC = 4, KQ = 32;
    __shared__ short Asl[64 * KD];    // 16 KB: s1 frags, then h1 tile
    __shared__ float scb[KD];
    __shared__ float shb[KD];

    const int t = threadIdx.x;
    const int l = t & 63;
    const int w = t >> 6;

    // B frags in registers
    short8 B1[2][KC];   // w1b: col-tiles {2w, 2w+1}
    short8 B2[KC];      // w2a: col-tile w
#pragma unroll
    for (int c = 0; c < 2; c++)
#pragma unroll
        for (int kc = 0; kc < KC; kc++)
            B1[c][kc] = *(const short8*)&w1bf[(((w * 2 + c) * KC + kc) * 64 + l) * 8];
#pragma unroll
    for (int kc = 0; kc < KC; kc++)
        B2[kc] = *(const short8*)&w2af[((w * KC + kc) * 64 + l) * 8];

    if (t < KD) {
        const float m = sum[t] * invN;
        const float v = sumsq[t] * invN - m * m;
        const float r = rsqrtf(v + 1e-5f);
        const float s = g[t] * r;
        scb[t] = s;
        shb[t] = be[t] - m * s;
    }
    __syncthreads();

    // stage A = BN+ReLU(s1) frags
    {
        const int r = t >> 2;
        const int q = t & 3;
        const int grow = blockIdx.x * 64 + r;
        const int rt = r >> 4;
        u16 hv[KQ];
        if (grow < M) {
            const u16* ap = s1 + (size_t)grow * KD + q * KQ;
#pragma unroll
            for (int i = 0; i < KQ / 8; i++)
                *(short8*)&hv[i * 8] = ((const short8*)ap)[i];
#pragma unroll
            for (int i = 0; i < KQ; i++) {
                const int k = q * KQ + i;
                hv[i] = f2bf(fmaxf(0.f, bf2f(hv[i]) * scb[k] + shb[k]));
            }
        } else {
#pragma unroll
            for (int i = 0; i < KQ; i++) hv[i] = 0;
        }
#pragma unroll
        for (int gg = 0; gg < KQ / 8; gg++) {
            const int k0 = q * KQ + gg * 8;
            const int kc = k0 >> 5;
            const int lane = (r & 15) + ((k0 >> 3) & 3) * 16;
            *(short8*)&Asl[((rt * KC + kc) * 64 + lane) * 8] = *(short8*)&hv[gg * 8];
        }
    }
    __syncthreads();

    // ---- MFMA stage 1: 128 -> 128 (wave w: all 4 row-tiles x its 2 cts) ----
    f32x4 acc[4][2];
#pragma unroll
    for (int rt = 0; rt < 4; rt++)
#pragma unroll
        for (int c = 0; c < 2; c++) acc[rt][c] = (f32x4){0.f, 0.f, 0.f, 0.f};
#pragma unroll
    for (int kc = 0; kc < KC; kc++)
#pragma unroll
        for (int rt = 0; rt < 4; rt++) {
            const short8 x0 = *(const short8*)&Asl[((rt * KC + kc) * 64 + l) * 8];
            acc[rt][0] = __builtin_amdgcn_mfma_f32_16x16x32_bf16(B1[0][kc], x0, acc[rt][0], 0, 0, 0);
            acc[rt][1] = __builtin_amdgcn_mfma_f32_16x16x32_bf16(B1[1][kc], x0, acc[rt][1], 0, 0, 0);
        }
    __syncthreads();   // all waves done reading Asl

    // ---- h1 tile -> Asl (row-major [64][128] bf16, granule-XOR swizzle) ----
    {
        const int cb4 = l >> 4;
#pragma unroll
        for (int rt = 0; rt < 4; rt++) {
            const int row = rt * 16 + (l & 15);
            const int sw = (row & 7) << 1;
#pragma unroll
            for (int c = 0; c < 2; c++) {
                const int ct = w * 2 + c;
                const float4 bv = *(const float4*)&b1b[ct * 16 + cb4 * 4];
                short4v o16;
                o16[0] = (short)f2bf(fmaxf(acc[rt][c][0] + bv.x, 0.f));
                o16[1] = (short)f2bf(fmaxf(acc[rt][c][1] + bv.y, 0.f));
                o16[2] = (short)f2bf(fmaxf(acc[rt][c][2] + bv.z, 0.f));
                o16[3] = (short)f2bf(fmaxf(acc[rt][c][3] + bv.w, 0.f));
                const int gsw = (ct * 4 + cb4) ^ sw;
                *(short4v*)&Asl[row * 128 + gsw * 4] = o16;
            }
        }
    }
    __syncthreads();

    // ---- MFMA stage 2: 128 -> 64 (wave w: 4 row-tiles x col-tile w) ----
    f32x4 acc2[4];
#pragma unroll
    for (int rt = 0; rt < 4; rt++) acc2[rt] = (f32x4){0.f, 0.f, 0.f, 0.f};
#pragma unroll
    for (int kc = 0; kc < KC; kc++)
#pragma unroll
        for (int rt = 0; rt < 4; rt++) {
            const int row = rt * 16 + (l & 15);
            const int G = kc * 8 + (l >> 4) * 2;
            const int Gs = G ^ ((row & 7) << 1);
            const short8 x0 = *(const short8*)&Asl[row * 128 + Gs * 4];
            acc2[rt] = __builtin_amdgcn_mfma_f32_16x16x32_bf16(B2[kc], x0, acc2[rt], 0, 0, 0);
        }

    // ---- epilogue: p2 bf16 ----
    {
        const int cbase = (l >> 4) * 4;
#pragma unroll
        for (int rt = 0; rt < 4; rt++) {
            const int grow = blockIdx.x * 64 + rt * 16 + (l & 15);
            if (grow < M) {
                short4v o16;
#pragma unroll
                for (int j = 0; j < 4; j++) o16[j] = (short)f2bf(acc2[rt][j]);
                *(short4v*)&p2[(size_t)grow * NO + w * 16 + cbase] = o16;
            }
        }
    }
}

// ---------------------------------------------------------------------------
// mgemm4 (old all-col-tile structure; needed for per-wave row log-softmax):
// out = log_softmax( relu(BN(s2)) @ w2b + b2b ).  LDS 16KB -> fine.
// ---------------------------------------------------------------------------
__global__ __launch_bounds__(256) void mgemm4_k(
    const u16* __restrict__ s2, const short* __restrict__ Wf,
    const float* __restrict__ sum, const float* __restrict__ sumsq,
    const float* __restrict__ g, const float* __restrict__ be, float invN,
    const float* __restrict__ bias, float* __restrict__ outp, int M)
{
    constexpr int KD = 64, NC = 64, KC = 2, CT = 4, KQ = 16;
    __shared__ short Asl[64 * KD];
    __shared__ short Bsl[NC * KD];
    __shared__ float scb[KD];
    __shared__ float shb[KD];

    const int t = threadIdx.x;
    const int l = t & 63;
    const int w = t >> 6;

    if (t < KD) {
        const float m = sum[t] * invN;
        const float v = sumsq[t] * invN - m * m;
        const float r = rsqrtf(v + 1e-5f);
        const float s = g[t] * r;
        scb[t] = s;
        shb[t] = be[t] - m * s;
    }
    __syncthreads();

    {
        const float4* src = (const float4*)Wf;
        float4* dst = (float4*)Bsl;
#pragma unroll
        for (int u = t; u < NC * KD / 8; u += 256) dst[u] = src[u];
    }
    {
        const int r = t >> 2;
        const int q = t & 3;
        const int grow = blockIdx.x * 64 + r;
        const int rt = r >> 4;
        u16 hv[KQ];
        if (grow < M) {
            const u16* ap = s2 + (size_t)grow * KD + q * KQ;
#pragma unroll
            for (int i = 0; i < KQ / 8; i++)
                *(short8*)&hv[i * 8] = ((const short8*)ap)[i];
#pragma unroll
            for (int i = 0; i < KQ; i++) {
                const int k = q * KQ + i;
                hv[i] = f2bf(fmaxf(0.f, bf2f(hv[i]) * scb[k] + shb[k]));
            }
        } else {
#pragma unroll
            for (int i = 0; i < KQ; i++) hv[i] = 0;
        }
#pragma unroll
        for (int gg = 0; gg < KQ / 8; gg++) {
            const int k0 = q * KQ + gg * 8;
            const int kc = k0 >> 5;
            const int lane = (r & 15) + ((k0 >> 3) & 3) * 16;
            *(short8*)&Asl[((rt * KC + kc) * 64 + lane) * 8] = *(short8*)&hv[gg * 8];
        }
    }
    __syncthreads();

    f32x4 acc[CT];
#pragma unroll
    for (int c = 0; c < CT; c++) acc[c] = (f32x4){0.f, 0.f, 0.f, 0.f};
#pragma unroll
    for (int kc = 0; kc < KC; kc++) {
        const short8 x0 = *(const short8*)&Asl[((w * KC + kc) * 64 + l) * 8];
#pragma unroll
        for (int ct = 0; ct < CT; ct++) {
            const short8 wb = *(const short8*)&Bsl[((ct * KC + kc) * 64 + l) * 8];
            acc[ct] = __builtin_amdgcn_mfma_f32_16x16x32_bf16(wb, x0, acc[ct], 0, 0, 0);
        }
    }

    const int cbase = (l >> 4) * 4;
    const int grow = blockIdx.x * 64 + w * 16 + (l & 15);
    float v[CT * 4];
#pragma unroll
    for (int ct = 0; ct < CT; ct++) {
        const float4 bv = *(const float4*)&bias[ct * 16 + cbase];
        v[ct * 4 + 0] = acc[ct][0] + bv.x;
        v[ct * 4 + 1] = acc[ct][1] + bv.y;
        v[ct * 4 + 2] = acc[ct][2] + bv.z;
        v[ct * 4 + 3] = acc[ct][3] + bv.w;
    }
    float m = v[0];
#pragma unroll
    for (int j = 1; j < CT * 4; j++) m = fmaxf(m, v[j]);
    m = fmaxf(m, __shfl_xor(m, 16));
    m = fmaxf(m, __shfl_xor(m, 32));
    float s = 0.f;
#pragma unroll
    for (int j = 0; j < CT * 4; j++) s += __expf(v[j] - m);
    s += __shfl_xor(s, 16);
    s += __shfl_xor(s, 32);
    const float lg = m + __logf(s);
    if (grow < M) {
#pragma unroll
        for (int ct = 0; ct < CT; ct++) {
            f32x4 o;
#pragma unroll
            for (int j = 0; j < 4; j++) o[j] = v[ct * 4 + j] - lg;
            *(f32x4*)&outp[(size_t)grow * NC + ct * 16 + cbase] = o;
        }
    }
}

// ---------------------------------------------------------------------------
// CSR build: histogram (also zeroes agg), ONE-kernel scan, bucket fill.
// ---------------------------------------------------------------------------
__global__ __launch_bounds__(256) void hist_k(const int* __restrict__ ei,
                                              int* __restrict__ cnt,
                                              int* __restrict__ agg, int E)
{
    const int gid = blockIdx.x * blockDim.x + threadIdx.x;
    if (gid < 256) agg[gid] = 0;
    const int stride = gridDim.x * blockDim.x;
    for (int e = gid; e < E; e += stride) atomicAdd(&cnt[ei[E + e]], 1);
}

// Single-kernel exclusive scan over cnt[0..N): 196 blocks (all co-resident).
// Each block publishes its aggregate (flag bit 30, release); polls all
// predecessors' aggregates (acquire); writes off/cursor.
__global__ __launch_bounds__(256) void scan1_k(const int* __restrict__ cnt,
                                               int* __restrict__ agg,
                                               int* __restrict__ off,
                                               int* __restrict__ cursor,
                                               int N, int E)
{
    __shared__ int part[256];
    __shared__ int redu[256];
    const int t = threadIdx.x;
    const int b = blockIdx.x;
    const int i = b * 256 + t;
    const int v = (i < N) ? cnt[i] : 0;
    part[t] = v;
    __syncthreads();
    for (int d = 1; d < 256; d <<= 1) {
        const int u = (t >= d) ? part[t - d] : 0;
        __syncthreads();
        part[t] += u;
        __syncthreads();
    }
    if (t == 0)
        __hip_atomic_store(&agg[b], part[255] | (1 << 30), __ATOMIC_RELEASE,
                           __HIP_MEMORY_SCOPE_AGENT);
    // poll predecessors (striped over threads)
    int loc = 0;
    for (int pb = t; pb < b; pb += 256) {
        int a;
        do {
            a = __hip_atomic_load(&agg[pb], __ATOMIC_ACQUIRE,
                                  __HIP_MEMORY_SCOPE_AGENT);
        } while (!(a & (1 << 30)));
        loc += a & ((1 << 30) - 1);
    }
    redu[t] = loc;
    __syncthreads();
    for (int s = 128; s; s >>= 1) {
        if (t < s) redu[t] += redu[t + s];
        __syncthreads();
    }
    const int base = redu[0];
    if (i < N) {
        const int o = base + part[t] - v;   // exclusive prefix
        off[i] = o;
        cursor[i] = o;
    }
    if (b == 0 && t == 0) off[N] = E;
}

__global__ __launch_bounds__(256) void fill_k(const int* __restrict__ ei,
                                              int* __restrict__ cursor,
                                              int* __restrict__ srcs, int E)
{
    const int gid = blockIdx.x * blockDim.x + threadIdx.x;
    const int stride = gridDim.x * blockDim.x;
    for (int e = gid; e < E; e += stride) {
        const int s = ei[e];
        const int d = ei[E + e];
        const int pos = atomicAdd(&cursor[d], 1);
        srcs[pos] = s;
    }
}

// ---------------------------------------------------------------------------
// Gather segment-sum (bf16 in/out) + fused column stats.  [R5 measured-best:
// BLKN=8, ~37% occupancy sweet spot — do not change]
// ---------------------------------------------------------------------------
template <int C>
__global__ __launch_bounds__(256) void segsum_bf(
    const u16* __restrict__ p, const int* __restrict__ off,
    const int* __restrict__ srcs, u16* __restrict__ out,
    float* __restrict__ sum, float* __restrict__ sumsq, int N)
{
    constexpr int BLKN = 8;            // nodes per wave
    constexpr int VPL = C / 64;        // channels per lane (2 or 1)
    __shared__ float red[4][64][2 * VPL];

    const int wv = threadIdx.x >> 6;
    const int l  = threadIdx.x & 63;
    const int base = blockIdx.x * 4 * BLKN;

    float ss[VPL], qq[VPL];
#pragma unroll
    for (int v = 0; v < VPL; v++) { ss[v] = 0.f; qq[v] = 0.f; }

    for (int i = 0; i < BLKN; i++) {
        const int n = base + i * 4 + wv;
        if (n < N) {
            const int lo = __builtin_amdgcn_readfirstlane(off[n]);
            const int hi = __builtin_amdgcn_readfirstlane(off[n + 1]);
            float acc[VPL];
            if constexpr (VPL == 2) {
                const u32 u = *(const u32*)&p[(size_t)n * C + 2 * l];
                acc[0] = bf2f((u16)u);
                acc[1] = bf2f((u16)(u >> 16));
            } else {
                acc[0] = bf2f(p[(size_t)n * C + l]);
            }
            const int cnt = hi - lo;
            if (cnt > 0) {
                const int last = hi - 1;
                int idx[8];
#pragma unroll
                for (int j = 0; j < 8; j++) idx[j] = srcs[min(lo + j, last)];
                for (int e = lo; e < hi; e += 8) {
                    int nx[8];
#pragma unroll
                    for (int j = 0; j < 8; j++)
                        nx[j] = srcs[min(e + 8 + j, last)];   // prefetch next
#pragma unroll
                    for (int j = 0; j < 8; j++) {
                        const bool live = (e + j) < hi;
                        if constexpr (VPL == 2) {
                            const u32 u = *(const u32*)&p[(size_t)idx[j] * C + 2 * l];
                            const float v0 = bf2f((u16)u);
                            const float v1 = bf2f((u16)(u >> 16));
                            acc[0] += live ? v0 : 0.f;
                            acc[1] += live ? v1 : 0.f;
                        } else {
                            const float v = bf2f(p[(size_t)idx[j] * C + l]);
                            acc[0] += live ? v : 0.f;
                        }
                    }
#pragma unroll
                    for (int j = 0; j < 8; j++) idx[j] = nx[j];
                }
            }
            if constexpr (VPL == 2) {
                const u16 r0 = f2bf(acc[0]);
                const u16 r1 = f2bf(acc[1]);
                *(u32*)&out[(size_t)n * C + 2 * l] = (u32)r0 | ((u32)r1 << 16);
                const float f0 = bf2f(r0), f1 = bf2f(r1);
                ss[0] += f0; qq[0] += f0 * f0;
                ss[1] += f1; qq[1] += f1 * f1;
            } else {
                const u16 r = f2bf(acc[0]);
                out[(size_t)n * C + l] = r;
                const float f = bf2f(r);
                ss[0] += f; qq[0] += f * f;
            }
        }
    }

#pragma unroll
    for (int v = 0; v < VPL; v++) {
        red[wv][l][2 * v] = ss[v];
        red[wv][l][2 * v + 1] = qq[v];
    }
    __syncthreads();
    if (wv == 0) {
#pragma unroll
        for (int v = 0; v < VPL; v++) {
            float a = 0.f, b = 0.f;
#pragma unroll
            for (int w2 = 0; w2 < 4; w2++) {
                a += red[w2][l][2 * v];
                b += red[w2][l][2 * v + 1];
            }
            const int ch = (VPL == 2) ? (2 * l + v) : l;
            atomAddF(&sum[ch], a);
            atomAddF(&sumsq[ch], b);
        }
    }
}

extern "C" void kernel_launch(void* const* d_in, const int* in_sizes, int n_in,
                              void* d_out, int out_size, void* d_ws, size_t ws_size,
                              hipStream_t stream)
{
    const float* x   = (const float*)d_in[0];
    const int*   ei  = (const int*)d_in[1];
    const float* w1a = (const float*)d_in[2];
    // d_in[3] = b1a: cancelled by BN
    const float* g1  = (const float*)d_in[4];
    const float* be1 = (const float*)d_in[5];
    const float* w1b = (const float*)d_in[6];
    const float* b1b = (const float*)d_in[7];
    const float* w2a = (const float*)d_in[8];
    // d_in[9] = b2a: cancelled by BN
    const float* g2  = (const float*)d_in[10];
    const float* be2 = (const float*)d_in[11];
    const float* w2b = (const float*)d_in[12];
    const float* b2b = (const float*)d_in[13];
    float* out = (float*)d_out;

    const int N = in_sizes[0] / 128;   // 50000
    const int E = in_sizes[1] / 2;     // 800000

    // ---- workspace layout ----
    u16* buf1 = (u16*)d_ws;                      // N*128 bf16 : p1, then p2
    u16* buf2 = buf1 + (size_t)N * 128;          // N*128 bf16 : s1, then s2
    float* stats = (float*)(buf2 + (size_t)N * 128);  // 1024 floats
    float* sum1 = stats,       *sq1 = stats + 128;
    float* sum2 = stats + 256, *sq2 = stats + 320;
    int* cnt    = (int*)(stats + 1024);          // N
    int* off    = cnt + N;                       // N+1
    int* cursor = off + N + 1;                   // N
    int* srcs   = cursor + N;                    // E
    int* agg    = srcs + E;                      // 256 (scan aggregates)
    int* bpre   = agg + 256;                     // 256 (unused, kept)
    short* w1af = (short*)(bpre + 256);          // 128*128
    short* w1bf = w1af + 128 * 128;              // 128*128
    short* w2af = w1bf + 128 * 128;              // 128*64
    short* w2bf = w2af + 128 * 64;               // 64*64
    u16* p1 = buf1;
    u16* s1 = buf2;
    u16* p2 = buf1;                    // reuse: p1 dead after segsum1
    u16* s2 = buf2;                    // reuse: s1 dead after mgemm23

    hipMemsetAsync(stats, 0, 1024 * sizeof(float) + (size_t)N * sizeof(int), stream);

    const int G1 = (N + 255) / 256;    // 196 blocks <= 256 CUs: co-resident
    const int gb = (N + 63) / 64;      // BM=64 -> 782 blocks
    const int gs = (N + 31) / 32;      // segsum: 4 waves x 8 nodes per block
    const float invN = 1.f / N;

    // ---- CSR build ----
    hist_k<<<1024, 256, 0, stream>>>(ei, cnt, agg, E);
    scan1_k<<<G1, 256, 0, stream>>>(cnt, agg, off, cursor, N, E);
    fill_k<<<1024, 256, 0, stream>>>(ei, cursor, srcs, E);

    // ---- weight prep (one launch for all four) ----
    wprep4_k<<<22, 256, 0, stream>>>(w1a, w1b, w2a, w2b, w1af, w1bf, w2af, w2bf);

    // ---- Layer 1 ----
    mgemm1_k<<<gb, 256, 0, stream>>>(x, w1af, p1, N);
    segsum_bf<128><<<gs, 256, 0, stream>>>(p1, off, srcs, s1, sum1, sq1, N);

    // ---- Fused: h1 = relu(BN(s1)@w1b+b1b); p2 = h1@w2a ----
    mgemm23_k<<<gb, 256, 0, stream>>>(s1, w1bf, w2af, sum1, sq1, g1, be1,
                                      invN, b1b, p2, N);

    // ---- Layer 2 aggregation + output ----
    segsum_bf<64><<<gs, 256, 0, stream>>>(p2, off, srcs, s2, sum2, sq2, N);
    mgemm4_k<<<gb, 256, 0, stream>>>(s2, w2bf, sum2, sq2, g2, be2, invN, b2b,
                                     out, N);
}